// Round 12
// baseline (927.774 us; speedup 1.0000x reference)
//
#include <hip/hip_runtime.h>
#include <hip/hip_bf16.h>
#include <math.h>

#define E_ 4
#define N_ 2048
#define D_ 256
#define H_ 8
#define F_ 2048
#define M_ 4096
#define L_ 3
#define GAMMA_ 0.1f
#define EPS_ 1e-5f
#define CCH 8   // cross-attention key chunks

#define GF_ATOMIC 1
#define GF_RELU   2

typedef __attribute__((ext_vector_type(8))) short  sh8;
typedef __attribute__((ext_vector_type(4))) float  fx4;
typedef __hip_bfloat16 bf16;

#define MFMA16 __builtin_amdgcn_mfma_f32_16x16x32_bf16

__device__ inline void gload_lds16(const void* g, void* l) {
    __builtin_amdgcn_global_load_lds((const __attribute__((address_space(1))) void*)g,
                                     (__attribute__((address_space(3))) void*)l, 16, 0, 0);
}

// Stage a [64][256] bf16 tile (row stride 512B) into LDS, XOR-swizzled source.
__device__ inline void stage_k64(const bf16* __restrict__ gbase, bf16* lds, int tid) {
    #pragma unroll
    for (int i = 0; i < 8; ++i) {
        int q = i * 256 + tid;
        int row = q >> 5, cst = q & 31;
        int cl = cst ^ (row & 7);
        gload_lds16((const char*)gbase + row * 512 + cl * 16, (char*)lds + q * 16);
    }
}
// Read staged K tile: row, k-slice = ks*32 + hi*8 elements.
__device__ inline sh8 ldsK(const bf16* lds, int row, int ks, int hi) {
    return *(const sh8*)((const char*)lds + row * 512 + (((ks * 4 + hi) ^ (row & 7)) << 4));
}

// Stage a [256][64] bf16 tile (d-major; source row stride = rstride elems) into LDS.
__device__ inline void stage_v64(const bf16* __restrict__ gbase, long rstride, bf16* lds, int tid) {
    #pragma unroll
    for (int i = 0; i < 8; ++i) {
        int q = i * 256 + tid;          // chunk 0..2047
        int row = q >> 3, cst = q & 7;
        int cl = cst ^ (row & 7);
        gload_lds16((const char*)(gbase + (long)row * rstride + cl * 8), (char*)lds + q * 16);
    }
}
// Read staged V tile: row in [0,256) (d), k-slice = ks*32 + hi*8 (n within 64).
__device__ inline sh8 ldsV(const bf16* lds, int row, int ks, int hi) {
    return *(const sh8*)((const char*)lds + row * 128 + (((ks * 4 + hi) ^ (row & 7)) << 4));
}

// ---------------------------------------------------------------------------
// bf16 MFMA GEMM
// ---------------------------------------------------------------------------
template<int BN>
__global__ __launch_bounds__(256, 4)
void gemm_bf16(const bf16* __restrict__ A, int lda,
               const bf16* __restrict__ Bt, int ldb, long wstride,
               float* C, int ldc, bf16* Cbf,
               int M, int N, int K, int Kc,
               float alpha, const float* __restrict__ bias, long bstride,
               const float* res, int ldres, int flags,
               const bf16* __restrict__ zerobuf)
{
    constexpr int MI  = (BN == 128) ? 4 : 2;
    constexpr int BCH = BN * 8 / 256;
    __shared__ char smem[16384 + BN * 128];
    char* sA = smem;
    char* sB = smem + 16384;
    const int tid  = threadIdx.x;
    const int lane = tid & 63;
    const int lo   = lane & 15, hi = lane >> 4;
    const int wid  = tid >> 6;
    const int rowbase = (BN == 128) ? (wid >> 1) * 64 : wid * 32;
    const int colbase = (BN == 128) ? (wid & 1) * 64 : 0;
    const int bm = blockIdx.y * 128, bn = blockIdx.x * BN;

    const int eid = (blockIdx.y * 128) >> 11;
    const bf16* Bte = Bt + (long)eid * wstride;
    const float* biase = bias ? (bias + (long)eid * bstride) : nullptr;

    const int kbeg = blockIdx.z * Kc;
    const int kend = min(K, kbeg + Kc);

    fx4 acc[MI][4] = {};

    for (int k0 = kbeg; k0 < kend; k0 += 64) {
        #pragma unroll
        for (int i = 0; i < 4; ++i) {
            int id  = i * 256 + tid;
            int row = id >> 3;
            int c   = (id & 7) ^ (row & 7);
            int gk  = k0 + c * 8;
            const bf16* gp = (gk < kend) ? (A + (long)(bm + row) * lda + gk) : zerobuf;
            gload_lds16(gp, sA + id * 16);
        }
        #pragma unroll
        for (int i = 0; i < BCH; ++i) {
            int id  = i * 256 + tid;
            int row = id >> 3;
            int c   = (id & 7) ^ (row & 7);
            int gk  = k0 + c * 8;
            const bf16* gp = (gk < kend && bn + row < N) ? (Bte + (long)(bn + row) * ldb + gk)
                                                         : zerobuf;
            gload_lds16(gp, sB + id * 16);
        }
        asm volatile("s_waitcnt vmcnt(0)" ::: "memory");
        __syncthreads();

        #pragma unroll
        for (int kk = 0; kk < 2; ++kk) {
            const int ko = kk * 32 + hi * 8;
            sh8 af[MI], bfr[4];
            #pragma unroll
            for (int i = 0; i < MI; ++i) {
                int row = rowbase + i * 16 + lo;
                int off = (row * 128 + ko * 2) ^ ((row & 7) << 4);
                af[i] = *(const sh8*)(sA + off);
            }
            #pragma unroll
            for (int j = 0; j < 4; ++j) {
                int row = colbase + j * 16 + lo;
                int off = (row * 128 + ko * 2) ^ ((row & 7) << 4);
                bfr[j] = *(const sh8*)(sB + off);
            }
            #pragma unroll
            for (int i = 0; i < MI; ++i)
                #pragma unroll
                for (int j = 0; j < 4; ++j)
                    acc[i][j] = MFMA16(af[i], bfr[j], acc[i][j], 0, 0, 0);
        }
        __syncthreads();
    }

    const bool z0 = (blockIdx.z == 0);
    #pragma unroll
    for (int j = 0; j < 4; ++j) {
        int col = bn + colbase + j * 16 + lo;
        if (col >= N) continue;
        #pragma unroll
        for (int i = 0; i < MI; ++i) {
            #pragma unroll
            for (int r = 0; r < 4; ++r) {
                int row = bm + rowbase + i * 16 + hi * 4 + r;
                float v = alpha * acc[i][j][r];
                if (z0) {
                    if (biase) v += biase[col];
                    if (res)   v += res[(long)row * ldres + col];
                }
                if (flags & GF_RELU) v = fmaxf(v, 0.f);
                long idx = (long)row * ldc + col;
                if (flags & GF_ATOMIC) atomicAdd(&C[idx], v);
                else {
                    if (C)   C[idx] = v;
                    if (Cbf) Cbf[idx] = __float2bfloat16(v);
                }
            }
        }
    }
}

// ---------------------------------------------------------------------------
// Flash MHA (unstaged: K/V are L2-resident; padded Plds).
// ---------------------------------------------------------------------------
__global__ __launch_bounds__(256, 4)
void flash_mha(const bf16* __restrict__ qkv, const bf16* __restrict__ vT,
               bf16* __restrict__ obuf)
{
    const int e = blockIdx.z, h = blockIdx.y;
    const int n0 = blockIdx.x * 64;
    const int tid = threadIdx.x, lane = tid & 63, w = tid >> 6;
    const int lo = lane & 15, hi = lane >> 4;
    const float scaleH = 0.17677669529663687f;
    const bf16* qkv_e = qkv + (long)e * N_ * 768;
    const bf16* vT_eh = vT + ((long)e * D_ + h * 32) * N_;
    __shared__ bf16 Plds[4][16][72];

    sh8 qf = *(const sh8*)(qkv_e + (long)(n0 + w * 16 + lo) * 768 + h * 32 + hi * 8);

    float m[4], l[4];
    fx4 acc[2] = {};
    #pragma unroll
    for (int r = 0; r < 4; ++r) { m[r] = -INFINITY; l[r] = 0.f; }

    for (int kc = 0; kc < N_; kc += 64) {
        float sv[4][4], rmax[4], rsum[4];
        #pragma unroll
        for (int j = 0; j < 4; ++j) {
            sh8 kf = *(const sh8*)(qkv_e + (long)(kc + j * 16 + lo) * 768 + 256 + h * 32 + hi * 8);
            fx4 s = {};
            s = MFMA16(qf, kf, s, 0, 0, 0);
            #pragma unroll
            for (int r = 0; r < 4; ++r) sv[j][r] = s[r] * scaleH;
        }
        #pragma unroll
        for (int r = 0; r < 4; ++r)
            rmax[r] = fmaxf(fmaxf(sv[0][r], sv[1][r]), fmaxf(sv[2][r], sv[3][r]));
        #pragma unroll
        for (int d = 1; d < 16; d <<= 1)
            #pragma unroll
            for (int r = 0; r < 4; ++r) rmax[r] = fmaxf(rmax[r], __shfl_xor(rmax[r], d, 64));
        float sc[4];
        #pragma unroll
        for (int r = 0; r < 4; ++r) {
            float mn = fmaxf(m[r], rmax[r]);
            sc[r] = __expf(m[r] - mn);
            m[r] = mn; rsum[r] = 0.f;
        }
        #pragma unroll
        for (int j = 0; j < 4; ++j)
            #pragma unroll
            for (int r = 0; r < 4; ++r) {
                float p = __expf(sv[j][r] - m[r]);
                sv[j][r] = p; rsum[r] += p;
            }
        #pragma unroll
        for (int d = 1; d < 16; d <<= 1)
            #pragma unroll
            for (int r = 0; r < 4; ++r) rsum[r] += __shfl_xor(rsum[r], d, 64);
        #pragma unroll
        for (int r = 0; r < 4; ++r) l[r] = l[r] * sc[r] + rsum[r];
        #pragma unroll
        for (int j2 = 0; j2 < 2; ++j2)
            #pragma unroll
            for (int r = 0; r < 4; ++r) acc[j2][r] *= sc[r];
        #pragma unroll
        for (int j = 0; j < 4; ++j)
            #pragma unroll
            for (int r = 0; r < 4; ++r)
                Plds[w][hi * 4 + r][j * 16 + lo] = __float2bfloat16(sv[j][r]);
        asm volatile("s_waitcnt lgkmcnt(0)" ::: "memory");
        __builtin_amdgcn_sched_barrier(0);
        __builtin_amdgcn_s_setprio(1);
        #pragma unroll
        for (int ks = 0; ks < 2; ++ks) {
            sh8 pa = *(const sh8*)(&Plds[w][lo][ks * 32 + hi * 8]);
            #pragma unroll
            for (int j2 = 0; j2 < 2; ++j2) {
                sh8 vb = *(const sh8*)(vT_eh + (long)(j2 * 16 + lo) * N_ + kc + ks * 32 + hi * 8);
                acc[j2] = MFMA16(pa, vb, acc[j2], 0, 0, 0);
            }
        }
        __builtin_amdgcn_s_setprio(0);
    }
    #pragma unroll
    for (int j2 = 0; j2 < 2; ++j2)
        #pragma unroll
        for (int r = 0; r < 4; ++r) {
            long row = (long)e * N_ + n0 + w * 16 + hi * 4 + r;
            obuf[row * D_ + h * 32 + j2 * 16 + lo] = __float2bfloat16(acc[j2][r] / l[r]);
        }
}

// ---------------------------------------------------------------------------
// Flash cross-attention: grid (N/64, CCH, E). K + V tiles staged in LDS.
// ---------------------------------------------------------------------------
__global__ __launch_bounds__(256, 2)
void flash_cross(const bf16* __restrict__ tok, const bf16* __restrict__ tokT,
                 bf16* __restrict__ Opart, float2* __restrict__ ml)
{
    const int e = blockIdx.z, ch = blockIdx.y;
    const int n0 = blockIdx.x * 64;
    const int tid = threadIdx.x, lane = tid & 63, w = tid >> 6;
    const int lo = lane & 15, hi = lane >> 4;
    const float scaleD = 1.0f / 16.0f;
    __shared__ bf16 Kt[64 * 256];
    __shared__ bf16 Vt[256 * 64];
    __shared__ bf16 Plds[4][16][72];

    sh8 qf[8];
    {
        const bf16* qr = tok + ((long)e * N_ + n0 + w * 16 + lo) * D_;
        #pragma unroll
        for (int ks = 0; ks < 8; ++ks) qf[ks] = *(const sh8*)(qr + ks * 32 + hi * 8);
    }
    float m[4], l[4];
    fx4 acc[16] = {};
    #pragma unroll
    for (int r = 0; r < 4; ++r) { m[r] = -INFINITY; l[r] = 0.f; }

    for (int kc = ch * 768; kc < ch * 768 + 768; kc += 64) {
        const int seg = kc >> 11;
        const int src = (seg < e) ? seg : seg + 1;
        const int rowb = kc & 2047;
        stage_k64(tok + ((long)src * N_ + rowb) * D_, Kt, tid);
        stage_v64(tokT + (long)src * D_ * N_ + rowb, N_, Vt, tid);
        asm volatile("s_waitcnt vmcnt(0)" ::: "memory");
        __syncthreads();

        float sv[4][4], rmax[4], rsum[4];
        __builtin_amdgcn_s_setprio(1);
        #pragma unroll
        for (int j = 0; j < 4; ++j) {
            int krow = j * 16 + lo;
            fx4 s = {};
            #pragma unroll
            for (int ks = 0; ks < 8; ++ks) {
                sh8 kf = ldsK(Kt, krow, ks, hi);
                s = MFMA16(qf[ks], kf, s, 0, 0, 0);
            }
            #pragma unroll
            for (int r = 0; r < 4; ++r) sv[j][r] = s[r] * scaleD;
        }
        __builtin_amdgcn_s_setprio(0);
        #pragma unroll
        for (int r = 0; r < 4; ++r)
            rmax[r] = fmaxf(fmaxf(sv[0][r], sv[1][r]), fmaxf(sv[2][r], sv[3][r]));
        #pragma unroll
        for (int d = 1; d < 16; d <<= 1)
            #pragma unroll
            for (int r = 0; r < 4; ++r) rmax[r] = fmaxf(rmax[r], __shfl_xor(rmax[r], d, 64));
        float sc[4];
        #pragma unroll
        for (int r = 0; r < 4; ++r) {
            float mn = fmaxf(m[r], rmax[r]);
            sc[r] = __expf(m[r] - mn);
            m[r] = mn; rsum[r] = 0.f;
        }
        #pragma unroll
        for (int j = 0; j < 4; ++j)
            #pragma unroll
            for (int r = 0; r < 4; ++r) {
                float p = __expf(sv[j][r] - m[r]);
                sv[j][r] = p; rsum[r] += p;
            }
        #pragma unroll
        for (int d = 1; d < 16; d <<= 1)
            #pragma unroll
            for (int r = 0; r < 4; ++r) rsum[r] += __shfl_xor(rsum[r], d, 64);
        #pragma unroll
        for (int r = 0; r < 4; ++r) l[r] = l[r] * sc[r] + rsum[r];
        #pragma unroll
        for (int j2 = 0; j2 < 16; ++j2)
            #pragma unroll
            for (int r = 0; r < 4; ++r) acc[j2][r] *= sc[r];
        #pragma unroll
        for (int j = 0; j < 4; ++j)
            #pragma unroll
            for (int r = 0; r < 4; ++r)
                Plds[w][hi * 4 + r][j * 16 + lo] = __float2bfloat16(sv[j][r]);
        asm volatile("s_waitcnt lgkmcnt(0)" ::: "memory");
        __builtin_amdgcn_sched_barrier(0);
        __builtin_amdgcn_s_setprio(1);
        #pragma unroll
        for (int ks = 0; ks < 2; ++ks) {
            sh8 pa = *(const sh8*)(&Plds[w][lo][ks * 32 + hi * 8]);
            #pragma unroll
            for (int j2 = 0; j2 < 16; ++j2) {
                sh8 vb = ldsV(Vt, j2 * 16 + lo, ks, hi);
                acc[j2] = MFMA16(pa, vb, acc[j2], 0, 0, 0);
            }
        }
        __builtin_amdgcn_s_setprio(0);
        __syncthreads();
    }
    const long base = (long)ch * E_ * N_ + (long)e * N_ + n0 + w * 16;
    #pragma unroll
    for (int j2 = 0; j2 < 16; ++j2)
        #pragma unroll
        for (int r = 0; r < 4; ++r)
            Opart[(base + hi * 4 + r) * D_ + j2 * 16 + lo] = __float2bfloat16(acc[j2][r] / l[r]);
    if (lo == 0) {
        #pragma unroll
        for (int r = 0; r < 4; ++r) {
            float2 t; t.x = m[r]; t.y = l[r];
            ml[base + hi * 4 + r] = t;
        }
    }
}

// Merge chunk-partials + token residual.
__global__ void cross_merge(const bf16* __restrict__ Opart, const float2* __restrict__ ml,
                            const float* __restrict__ tokens,
                            float* __restrict__ x0f, bf16* __restrict__ x0bf)
{
    long row = blockIdx.x; int d = threadIdx.x;
    float2 v[CCH];
    float mx = -INFINITY;
    #pragma unroll
    for (int i = 0; i < CCH; ++i) { v[i] = ml[(long)i * E_ * N_ + row]; mx = fmaxf(mx, v[i].x); }
    float L = 0.f, o = 0.f;
    #pragma unroll
    for (int i = 0; i < CCH; ++i) {
        float wgt = v[i].y * __expf(v[i].x - mx);
        L += wgt;
        o += wgt * __bfloat162float(Opart[((long)i * E_ * N_ + row) * D_ + d]);
    }
    float val = tokens[row * D_ + d] + o / L;
    x0f[row * D_ + d] = val;
    x0bf[row * D_ + d] = __float2bfloat16(val);
}

// ---------------------------------------------------------------------------
// ret_flash (R11): per (q-tile, layer, e*2+mhalf). K + V staged. Deferred l-reduce.
// ---------------------------------------------------------------------------
__global__ __launch_bounds__(256, 2)
void ret_flash(const bf16* __restrict__ x2b, const bf16* __restrict__ memb,
               const bf16* __restrict__ maggT, bf16* __restrict__ OmemH,
               float* __restrict__ rsH)
{
    const int li = blockIdx.y;
    const int e = blockIdx.z >> 1, mh = blockIdx.z & 1;
    const int n0 = blockIdx.x * 64;
    const int tid = threadIdx.x, lane = tid & 63, w = tid >> 6;
    const int lo = lane & 15, hi = lane >> 4;
    const float scaleD = 1.0f / 16.0f;
    __shared__ bf16 Kt[64 * 256];
    __shared__ bf16 Vt[256 * 64];
    __shared__ bf16 Plds[4][16][72];

    sh8 qf[8];
    {
        const bf16* qr = x2b + ((long)e * N_ + n0 + w * 16 + lo) * D_;
        #pragma unroll
        for (int ks = 0; ks < 8; ++ks) qf[ks] = *(const sh8*)(qr + ks * 32 + hi * 8);
    }
    float l[4] = {0.f, 0.f, 0.f, 0.f};
    fx4 acc[16] = {};
    const bf16* Kl = memb + (long)li * M_ * D_;
    const bf16* Vl = maggT + (long)li * D_ * M_;
    const int mbase = mh * 2048;

    for (int t = 0; t < 32; ++t) {
        const int m0 = mbase + t * 64;
        stage_k64(Kl + (long)m0 * D_, Kt, tid);
        stage_v64(Vl + m0, M_, Vt, tid);
        asm volatile("s_waitcnt vmcnt(0)" ::: "memory");
        __syncthreads();

        __builtin_amdgcn_s_setprio(1);
        #pragma unroll
        for (int j = 0; j < 4; ++j) {
            int krow = j * 16 + lo;
            fx4 s = {};
            #pragma unroll
            for (int ks = 0; ks < 8; ++ks) {
                sh8 kf = ldsK(Kt, krow, ks, hi);
                s = MFMA16(qf[ks], kf, s, 0, 0, 0);
            }
            #pragma unroll
            for (int r = 0; r < 4; ++r) {
                float p = __expf(s[r] * scaleD);
                l[r] += p;
                Plds[w][hi * 4 + r][j * 16 + lo] = __float2bfloat16(p);
            }
        }
        __builtin_amdgcn_s_setprio(0);
        asm volatile("s_waitcnt lgkmcnt(0)" ::: "memory");
        __builtin_amdgcn_sched_barrier(0);
        __builtin_amdgcn_s_setprio(1);
        #pragma unroll
        for (int ks = 0; ks < 2; ++ks) {
            sh8 pa = *(const sh8*)(&Plds[w][lo][ks * 32 + hi * 8]);
            #pragma unroll
            for (int j2 = 0; j2 < 16; ++j2) {
                sh8 vb = ldsV(Vt, j2 * 16 + lo, ks, hi);
                acc[j2] = MFMA16(pa, vb, acc[j2], 0, 0, 0);
            }
        }
        __builtin_amdgcn_s_setprio(0);
        __syncthreads();
    }
    #pragma unroll
    for (int d = 1; d < 16; d <<= 1)
        #pragma unroll
        for (int r = 0; r < 4; ++r) l[r] += __shfl_xor(l[r], d, 64);

    const long rowb = ((long)(mh * 12 + e * L_ + li)) * N_ + n0 + w * 16;
    #pragma unroll
    for (int j2 = 0; j2 < 16; ++j2)
        #pragma unroll
        for (int r = 0; r < 4; ++r)
            OmemH[(rowb + hi * 4 + r) * D_ + j2 * 16 + lo] = __float2bfloat16(acc[j2][r]);
    if (lo == 0) {
        #pragma unroll
        for (int r = 0; r < 4; ++r)
            rsH[rowb + hi * 4 + r] = l[r];
    }
}

// rsinv[i] = 1/(rsH[i] + rsH[12N + i])  for i in [0, 12N)
__global__ void rsinv_kernel(const float* __restrict__ rsH, float* __restrict__ rsinv) {
    long i = (long)blockIdx.x * 256 + threadIdx.x;
    if (i < (long)12 * N_)
        rsinv[i] = 1.0f / (rsH[i] + rsH[(long)12 * N_ + i]);
}

// ---------------------------------------------------------------------------
// upd_flash v2: 256 thr, 4 waves × 32 m-rows (2 output fragments per wave) —
// each K/V LDS fragment feeds 2 MFMAs, halving LDS bytes/FLOP.
// __launch_bounds__(256,1): full 512-VGPR budget, 1 block/CU (LDS 101KB).
// grid (M/128, L, E). updpart[e][l][m][d] = (exp(mem@x2^T/16)*rsinv) @ x2.
// ---------------------------------------------------------------------------
__global__ __launch_bounds__(256, 1)
void upd_flash(const bf16* __restrict__ x2b, const bf16* __restrict__ memb,
               const bf16* __restrict__ x2T, const float* __restrict__ rsinv,
               bf16* __restrict__ updpart)
{
    const int li = blockIdx.y, e = blockIdx.z;
    const int m0 = blockIdx.x * 128;
    const int tid = threadIdx.x, lane = tid & 63, w = tid >> 6;
    const int lo = lane & 15, hi = lane >> 4;
    const float scaleD = 1.0f / 16.0f;
    __shared__ bf16 Kt[64 * 256];
    __shared__ bf16 Vt[256 * 64];
    __shared__ bf16 Plds[4][32][72];

    sh8 qf0[8], qf1[8];
    {
        const bf16* qr0 = memb + (long)li * M_ * D_ + (long)(m0 + w * 32 + lo) * D_;
        const bf16* qr1 = qr0 + 16 * D_;
        #pragma unroll
        for (int ks = 0; ks < 8; ++ks) {
            qf0[ks] = *(const sh8*)(qr0 + ks * 32 + hi * 8);
            qf1[ks] = *(const sh8*)(qr1 + ks * 32 + hi * 8);
        }
    }
    fx4 acc0[16] = {}, acc1[16] = {};
    const float* rse = rsinv + (long)(e * L_ + li) * N_;
    const bf16* x2Te = x2T + (long)e * D_ * N_;

    for (int t = 0; t < 32; ++t) {
        const int n0 = t * 64;
        stage_k64(x2b + ((long)e * N_ + n0) * D_, Kt, tid);
        stage_v64(x2Te + n0, N_, Vt, tid);
        float rinv[4];
        #pragma unroll
        for (int j = 0; j < 4; ++j) rinv[j] = rse[n0 + j * 16 + lo];
        asm volatile("s_waitcnt vmcnt(0)" ::: "memory");
        __syncthreads();

        __builtin_amdgcn_s_setprio(1);
        #pragma unroll
        for (int j = 0; j < 4; ++j) {
            int krow = j * 16 + lo;
            fx4 s0 = {}, s1 = {};
            #pragma unroll
            for (int ks = 0; ks < 8; ++ks) {
                sh8 kf = ldsK(Kt, krow, ks, hi);
                s0 = MFMA16(qf0[ks], kf, s0, 0, 0, 0);
                s1 = MFMA16(qf1[ks], kf, s1, 0, 0, 0);
            }
            #pragma unroll
            for (int r = 0; r < 4; ++r) {
                float p0 = __expf(s0[r] * scaleD) * rinv[j];
                float p1 = __expf(s1[r] * scaleD) * rinv[j];
                Plds[w][hi * 4 + r][j * 16 + lo]      = __float2bfloat16(p0);
                Plds[w][16 + hi * 4 + r][j * 16 + lo] = __float2bfloat16(p1);
            }
        }
        __builtin_amdgcn_s_setprio(0);
        asm volatile("s_waitcnt lgkmcnt(0)" ::: "memory");
        __builtin_amdgcn_sched_barrier(0);
        __builtin_amdgcn_s_setprio(1);
        #pragma unroll
        for (int ks = 0; ks < 2; ++ks) {
            sh8 pa0 = *(const sh8*)(&Plds[w][lo][ks * 32 + hi * 8]);
            sh8 pa1 = *(const sh8*)(&Plds[w][16 + lo][ks * 32 + hi * 8]);
            #pragma unroll
            for (int j2 = 0; j2 < 16; ++j2) {
                sh8 vb = ldsV(Vt, j2 * 16 + lo, ks, hi);
                acc0[j2] = MFMA16(pa0, vb, acc0[j2], 0, 0, 0);
                acc1[j2] = MFMA16(pa1, vb, acc1[j2], 0, 0, 0);
            }
        }
        __builtin_amdgcn_s_setprio(0);
        __syncthreads();
    }
    const long mrow = ((long)(e * L_ + li)) * M_ + m0 + w * 32;
    #pragma unroll
    for (int j2 = 0; j2 < 16; ++j2)
        #pragma unroll
        for (int r = 0; r < 4; ++r) {
            updpart[(mrow + hi * 4 + r) * D_ + j2 * 16 + lo]      = __float2bfloat16(acc0[j2][r]);
            updpart[(mrow + 16 + hi * 4 + r) * D_ + j2 * 16 + lo] = __float2bfloat16(acc1[j2][r]);
        }
}

// xfinal[e,n] += sum_l (O0+O1)*rsinv + agg_b
__global__ void retscale(const bf16* __restrict__ OmemH, const float* __restrict__ rsinv,
                         const float* __restrict__ aggb, float* __restrict__ xfinal)
{
    long row = blockIdx.x; int d = threadIdx.x;
    int e = (int)(row >> 11); long n = row & 2047;
    float s = aggb[d];
    #pragma unroll
    for (int li = 0; li < L_; ++li) {
        long r0 = ((long)(e * L_ + li)) * N_ + n;
        long r1 = ((long)(12 + e * L_ + li)) * N_ + n;
        float o = __bfloat162float(OmemH[r0 * D_ + d]) + __bfloat162float(OmemH[r1 * D_ + d]);
        s += o * rsinv[r0];
    }
    xfinal[row * D_ + d] += s;
}

// LayerNorm over D=256, per-expert weights (expert = row>>11). f32 + bf16 out.
__global__ void layernorm_rows(const float* __restrict__ X, const float* __restrict__ g,
                               const float* __restrict__ b, float* __restrict__ out,
                               bf16* __restrict__ outbf)
{
    __shared__ float red[256];
    int row = blockIdx.x, t = threadIdx.x;
    int e = row >> 11;
    float v = X[(long)row * 256 + t];
    red[t] = v; __syncthreads();
    for (int s = 128; s > 0; s >>= 1) { if (t < s) red[t] += red[t + s]; __syncthreads(); }
    float mu = red[0] * (1.0f / 256.0f); __syncthreads();
    float d = v - mu;
    red[t] = d * d; __syncthreads();
    for (int s = 128; s > 0; s >>= 1) { if (t < s) red[t] += red[t + s]; __syncthreads(); }
    float var = red[0] * (1.0f / 256.0f);
    float o = d * rsqrtf(var + EPS_) * g[e * 256 + t] + b[e * 256 + t];
    out[(long)row * 256 + t] = o;
    outbf[(long)row * 256 + t] = __float2bfloat16(o);
}

__global__ void cvt_bf16(const float* __restrict__ in, bf16* __restrict__ out, long n) {
    long i = ((long)blockIdx.x * 256 + threadIdx.x) * 4;
    if (i < n) {
        float4 v = *(const float4*)(in + i);
        out[i + 0] = __float2bfloat16(v.x);
        out[i + 1] = __float2bfloat16(v.y);
        out[i + 2] = __float2bfloat16(v.z);
        out[i + 3] = __float2bfloat16(v.w);
    }
}

__device__ inline float ldf(const float* p) { return *p; }
__device__ inline float ldf(const bf16* p)  { return __bfloat162float(*p); }

template<typename T>
__global__ void transpose_bf16(const T* __restrict__ in, bf16* __restrict__ out,
                               int R, int C, int ldin, int ldout) {
    __shared__ float t[64][65];
    int tx = threadIdx.x & 63, ty = threadIdx.x >> 6;
    int r0 = blockIdx.y * 64, c0 = blockIdx.x * 64;
    #pragma unroll
    for (int i = 0; i < 16; ++i) {
        int r = ty + i * 4;
        t[r][tx] = ldf(&in[(long)(r0 + r) * ldin + (c0 + tx)]);
    }
    __syncthreads();
    #pragma unroll
    for (int i = 0; i < 16; ++i) {
        int c = ty + i * 4;
        out[(long)(c0 + c) * ldout + (r0 + tx)] = __float2bfloat16(t[tx][c]);
    }
}

// out_mem = 0.9*mem + 0.1*sum_e updpart[e]
__global__ void mem_update(const float4* __restrict__ mem, const bf16* __restrict__ updpart,
                           float4* __restrict__ out) {
    long i = (long)blockIdx.x * 256 + threadIdx.x;
    const long LMD = (long)L_ * M_ * D_;
    if (i < LMD / 4) {
        float4 a = mem[i];
        float s0 = 0.f, s1 = 0.f, s2 = 0.f, s3 = 0.f;
        #pragma unroll
        for (int e = 0; e < E_; ++e) {
            const bf16* u = updpart + e * LMD + i * 4;
            s0 += __bfloat162float(u[0]);
            s1 += __bfloat162float(u[1]);
            s2 += __bfloat162float(u[2]);
            s3 += __bfloat162float(u[3]);
        }
        float4 r;
        r.x = (1.0f - GAMMA_) * a.x + GAMMA_ * s0;
        r.y = (1.0f - GAMMA_) * a.y + GAMMA_ * s1;
        r.z = (1.0f - GAMMA_) * a.z + GAMMA_ * s2;
        r.w = (1.0f - GAMMA_) * a.w + GAMMA_ * s3;
        out[i] = r;
    }
}

__global__ void pool_partial(const float* __restrict__ xf, float* __restrict__ pooled) {
    int e = blockIdx.x, chunk = blockIdx.y, t = threadIdx.x;
    float s = 0.f;
    int n0 = chunk * (N_ / 16);
    for (int n = n0; n < n0 + N_ / 16; ++n)
        s += xf[((long)e * N_ + n) * D_ + t];
    atomicAdd(&pooled[e * D_ + t], s * (1.0f / (float)N_));
}

__global__ void gate_kernel(const float* __restrict__ pooled, const float* __restrict__ gg,
                            float* __restrict__ out_gate, float* __restrict__ ws_gate) {
    __shared__ float red[256];
    __shared__ float logits[4];
    int t = threadIdx.x;
    for (int e = 0; e < 4; ++e) {
        red[t] = pooled[e * 256 + t] * gg[t];
        __syncthreads();
        for (int s = 128; s > 0; s >>= 1) { if (t < s) red[t] += red[t + s]; __syncthreads(); }
        if (t == 0) logits[e] = red[0];
        __syncthreads();
    }
    if (t == 0) {
        float mm = fmaxf(fmaxf(logits[0], logits[1]), fmaxf(logits[2], logits[3]));
        float g[4]; float s = 0.f;
        for (int e = 0; e < 4; ++e) { g[e] = __expf(logits[e] - mm); s += g[e]; }
        for (int e = 0; e < 4; ++e) {
            float w = g[e] / s;
            out_gate[e] = w;
            ws_gate[e] = w;
        }
    }
}

__global__ void fuse_kernel(const float* __restrict__ xf, const float* __restrict__ g4,
                            float* __restrict__ out) {
    long i = (long)blockIdx.x * 256 + threadIdx.x;
    const long ND = (long)N_ * D_;
    if (i < ND)
        out[i] = g4[0] * xf[i] + g4[1] * xf[ND + i] + g4[2] * xf[2 * ND + i] + g4[3] * xf[3 * ND + i];
}

// ---------------------------------------------------------------------------

static void gemm(hipStream_t s, int BN, const bf16* A, int lda, const bf16* Bt, int ldb,
                 long wstride, float* C, int ldc, bf16* Cbf, int M, int N, int K, int Kc,
                 float alpha, const float* bias, long bstride, const float* res, int ldres,
                 int flags, const bf16* zb) {
    dim3 g((N + BN - 1) / BN, (M + 127) / 128, (K + Kc - 1) / Kc);
    if (BN == 128)
        gemm_bf16<128><<<g, dim3(256), 0, s>>>(A, lda, Bt, ldb, wstride, C, ldc, Cbf, M, N, K, Kc,
                                               alpha, bias, bstride, res, ldres, flags, zb);
    else
        gemm_bf16<64><<<g, dim3(256), 0, s>>>(A, lda, Bt, ldb, wstride, C, ldc, Cbf, M, N, K, Kc,
                                              alpha, bias, bstride, res, ldres, flags, zb);
}

static void transposeF(hipStream_t s, const float* in, bf16* out, int R, int C, int ldin, int ldout) {
    transpose_bf16<float><<<dim3(C / 64, R / 64), dim3(256), 0, s>>>(in, out, R, C, ldin, ldout);
}
static void transposeB(hipStream_t s, const bf16* in, bf16* out, int R, int C, int ldin, int ldout) {
    transpose_bf16<bf16><<<dim3(C / 64, R / 64), dim3(256), 0, s>>>(in, out, R, C, ldin, ldout);
}
static void convert(hipStream_t s, const float* in, bf16* out, long n) {
    cvt_bf16<<<dim3((unsigned)((n / 4 + 255) / 256)), dim3(256), 0, s>>>(in, out, n);
}

extern "C" void kernel_launch(void* const* d_in, const int* in_sizes, int n_in,
                              void* d_out, int out_size, void* d_ws, size_t ws_size,
                              hipStream_t stream) {
    const float* tokens    = (const float*)d_in[0];
    const float* memories  = (const float*)d_in[1];
    const float* in_proj_w = (const float*)d_in[2];
    const float* in_proj_b = (const float*)d_in[3];
    const float* out_w     = (const float*)d_in[4];
    const float* out_b     = (const float*)d_in[5];
    const float* lin1_w    = (const float*)d_in[6];
    const float* lin1_b    = (const float*)d_in[7];
    const float* lin2_w    = (const float*)d_in[8];
    const float* lin2_b    = (const float*)d_in[9];
    const float* ln1_w     = (const float*)d_in[10];
    const float* ln1_b     = (const float*)d_in[11];
    const float* ln2_w     = (const float*)d_in[12];
    const float* ln2_b     = (const float*)d_in[13];
    const float* agg_w     = (const float*)d_in[14];
    const float* agg_b     = (const float*)d_in[15];
    const float* gg        = (const float*)d_in[16];

    char* p = (char*)d_ws;
    auto alloc = [&](size_t bytes) { char* r = p; p += (bytes + 255) & ~(size_t)255; return r; };

    // regionA (32MB), time-shared: Opart(cross) -> hid_all(FFN) -> OmemH(mem, bf16 halves)
    char*  regionA = alloc((size_t)32 * 1024 * 1024);
    bf16*  Opart   = (bf16*)regionA;                    // [8][E*N][256] bf16 = 32MB
    bf16*  hid_all = (bf16*)regionA;                    // [8192][2048] bf16 = 32MB
    bf16*  OmemH   = (bf16*)regionA;                    // [2][12][2048][256] bf16 = 25.2MB

    // regionB (32MB), time-shared: qkv|vT|obuf (MHA) -> updpart (mem)
    char*  regionB = alloc((size_t)32 * 1024 * 1024);
    bf16*  qkv_bf  = (bf16*)regionB;                              // 12.58MB
    bf16*  vT_bf   = (bf16*)(regionB + 12582912);                 // 4.19MB
    bf16*  obuf_bf = (bf16*)(regionB + 12582912 + 4194304);       // 4.19MB
    bf16*  updpart = (bf16*)regionB;                              // [4][3][4096][256] bf16 = 25.2MB

    float* xfinal  = (float*)alloc((size_t)E_ * N_ * D_ * 4);
    bf16*  x2_bf   = (bf16*)alloc((size_t)E_ * N_ * D_ * 2);
    bf16*  x2T_bf  = (bf16*)alloc((size_t)E_ * D_ * N_ * 2);
    float* x0f     = (float*)alloc((size_t)E_ * N_ * D_ * 4);
    bf16*  x0bf    = (bf16*)alloc((size_t)E_ * N_ * D_ * 2);
    float* ybuf    = (float*)alloc((size_t)E_ * N_ * D_ * 4);
    bf16*  tok_bf  = (bf16*)alloc((size_t)E_ * N_ * D_ * 2);
    bf16*  tokT_bf = (bf16*)alloc((size_t)E_ * D_ * N_ * 2);
    bf16*  mem_bf  = (bf16*)alloc((size_t)L_ * M_ * D_ * 2);
    bf16*  maggT   = (bf16*)alloc((size_t)L_ * D_ * M_ * 2);
    float2* mlbuf  = (float2*)alloc((size_t)CCH * E_ * N_ * sizeof(float2));
    float* rsH     = (float*)alloc((size_t)2 * 12 * N_ * 4);
    float* rsinv   = (float*)alloc((size_t)12 * N_ * 4);
    bf16*  ipw_bf  = (bf16*)alloc((size_t)E_ * 3 * D_ * D_ * 2);
    bf16*  outw_bf = (bf16*)alloc((size_t)E_ * D_ * D_ * 2);
    bf16*  l1w_bf  = (bf16*)alloc((size_t)E_ * F_ * D_ * 2);
    bf16*  l2w_bf  = (bf16*)alloc((size_t)E_ * D_ * F_ * 2);
    bf16*  aggw_bf = (bf16*)alloc((size_t)D_ * 3 * D_ * 2);
    float* pooled  = (float*)alloc(1024 * 4);
    float* gatebuf = (float*)alloc(64);
    bf16*  zerobuf = (bf16*)alloc(64);

    float* x1f  = x0f;
    bf16*  x1bf = x0bf;

    float* out_fused = (float*)d_out;
    float* out_gate  = out_fused + (long)N_ * D_;
    float* out_mem   = out_gate + E_;

    hipMemsetAsync(zerobuf, 0, 64, stream);
    hipMemsetAsync(pooled, 0, 1024 * 4, stream);

    // one-time conversions / transposes
    convert(stream, tokens, tok_bf, (long)E_ * N_ * D_);
    convert(stream, memories, mem_bf, (long)L_ * M_ * D_);
    convert(stream, in_proj_w, ipw_bf, (long)E_ * 3 * D_ * D_);
    convert(stream, out_w, outw_bf, (long)E_ * D_ * D_);
    convert(stream, lin1_w, l1w_bf, (long)E_ * F_ * D_);
    convert(stream, lin2_w, l2w_bf, (long)E_ * D_ * F_);
    convert(stream, agg_w, aggw_bf, (long)D_ * 3 * D_);
    for (int e = 0; e < E_; ++e)
        transposeF(stream, tokens + (long)e * N_ * D_, tokT_bf + (long)e * D_ * N_, N_, D_, D_, N_);
    // maggT_l = agg_w_l @ mem_l^T : [256, 4096]
    for (int l = 0; l < L_; ++l)
        gemm(stream, 128, aggw_bf + l * D_, 3 * D_, mem_bf + (long)l * M_ * D_, D_, 0,
             nullptr, M_, maggT + (long)l * D_ * M_, D_, M_, D_, D_,
             1.0f, nullptr, 0, nullptr, 0, 0, zerobuf);

    // ---- cross-expert attention ----
    flash_cross<<<dim3(N_ / 64, CCH, E_), dim3(256), 0, stream>>>(tok_bf, tokT_bf, Opart, mlbuf);
    cross_merge<<<dim3(E_ * N_), dim3(256), 0, stream>>>(Opart, mlbuf, tokens, x0f, x0bf);

    // ---- MHA (batched) ----
    gemm(stream, 128, x0bf, D_, ipw_bf, D_, (long)3 * D_ * D_,
         nullptr, 3 * D_, qkv_bf, E_ * N_, 3 * D_, D_, D_,
         1.0f, in_proj_b, 3 * D_, nullptr, 0, 0, zerobuf);
    for (int e = 0; e < E_; ++e)
        transposeB(stream, qkv_bf + (long)e * N_ * 3 * D_ + 2 * D_, vT_bf + (long)e * D_ * N_,
                   N_, D_, 3 * D_, N_);
    flash_mha<<<dim3(N_ / 64, H_, E_), dim3(256), 0, stream>>>(qkv_bf, vT_bf, obuf_bf);
    gemm(stream, 64, obuf_bf, D_, outw_bf, D_, (long)D_ * D_,
         ybuf, D_, nullptr, E_ * N_, D_, D_, D_,
         1.0f, out_b, D_, x0f, D_, 0, zerobuf);
    layernorm_rows<<<dim3(E_ * N_), dim3(256), 0, stream>>>(ybuf, ln1_w, ln1_b, x1f, x1bf);

    // ---- FFN (batched) ----
    gemm(stream, 128, x1bf, D_, l1w_bf, D_, (long)F_ * D_,
         nullptr, F_, hid_all, E_ * N_, F_, D_, D_,
         1.0f, lin1_b, F_, nullptr, 0, GF_RELU, zerobuf);
    hipMemsetAsync(ybuf, 0, (size_t)E_ * N_ * D_ * 4, stream);
    gemm(stream, 64, hid_all, F_, l2w_bf, F_, (long)D_ * F_,
         ybuf, D_, nullptr, E_ * N_, D_, F_, 512,
         1.0f, lin2_b, D_, x1f, D_, GF_ATOMIC, zerobuf);
    layernorm_rows<<<dim3(E_ * N_), dim3(256), 0, stream>>>(ybuf, ln2_w, ln2_b, xfinal, x2_bf);
    for (int e = 0; e < E_; ++e)
        transposeF(stream, xfinal + (long)e * N_ * D_, x2T_bf + (long)e * D_ * N_, N_, D_, D_, N_);

    // ---- memory read/write (flash, no-max softmax, store-only epilogues) ----
    ret_flash<<<dim3(N_ / 64, L_, E_ * 2), dim3(256), 0, stream>>>(x2_bf, mem_bf, maggT, OmemH, rsH);
    rsinv_kernel<<<dim3((12 * N_ + 255) / 256), dim3(256), 0, stream>>>(rsH, rsinv);
    upd_flash<<<dim3(M_ / 128, L_, E_), dim3(256), 0, stream>>>(x2_bf, mem_bf, x2T_bf, rsinv, updpart);
    retscale<<<dim3(E_ * N_), dim3(256), 0, stream>>>(OmemH, rsinv, agg_b, xfinal);

    mem_update<<<dim3(L_ * M_ * D_ / 4 / 256), dim3(256), 0, stream>>>(
        (const float4*)memories, updpart, (float4*)out_mem);
    pool_partial<<<dim3(E_, 16), dim3(256), 0, stream>>>(xfinal, pooled);
    gate_kernel<<<dim3(1), dim3(256), 0, stream>>>(pooled, gg, out_gate, gatebuf);
    fuse_kernel<<<dim3((N_ * D_ + 255) / 256), dim3(256), 0, stream>>>(xfinal, gatebuf, out_fused);
}

// Round 13
// 908.588 us; speedup vs baseline: 1.0211x; 1.0211x over previous
//
#include <hip/hip_runtime.h>
#include <hip/hip_bf16.h>
#include <math.h>

#define E_ 4
#define N_ 2048
#define D_ 256
#define H_ 8
#define F_ 2048
#define M_ 4096
#define L_ 3
#define GAMMA_ 0.1f
#define EPS_ 1e-5f
#define CCH 8   // cross-attention key chunks

#define GF_ATOMIC 1
#define GF_RELU   2

typedef __attribute__((ext_vector_type(8))) short  sh8;
typedef __attribute__((ext_vector_type(4))) float  fx4;
typedef __hip_bfloat16 bf16;

#define MFMA16 __builtin_amdgcn_mfma_f32_16x16x32_bf16

__device__ inline void gload_lds16(const void* g, void* l) {
    __builtin_amdgcn_global_load_lds((const __attribute__((address_space(1))) void*)g,
                                     (__attribute__((address_space(3))) void*)l, 16, 0, 0);
}

// Stage a [64][256] bf16 tile (row stride 512B) into LDS, XOR-swizzled source.
__device__ inline void stage_k64(const bf16* __restrict__ gbase, bf16* lds, int tid) {
    #pragma unroll
    for (int i = 0; i < 8; ++i) {
        int q = i * 256 + tid;
        int row = q >> 5, cst = q & 31;
        int cl = cst ^ (row & 7);
        gload_lds16((const char*)gbase + row * 512 + cl * 16, (char*)lds + q * 16);
    }
}
// Read staged K tile: row, k-slice = ks*32 + hi*8 elements.
__device__ inline sh8 ldsK(const bf16* lds, int row, int ks, int hi) {
    return *(const sh8*)((const char*)lds + row * 512 + (((ks * 4 + hi) ^ (row & 7)) << 4));
}

// Stage a [256][64] bf16 tile (d-major; source row stride = rstride elems) into LDS.
__device__ inline void stage_v64(const bf16* __restrict__ gbase, long rstride, bf16* lds, int tid) {
    #pragma unroll
    for (int i = 0; i < 8; ++i) {
        int q = i * 256 + tid;          // chunk 0..2047
        int row = q >> 3, cst = q & 7;
        int cl = cst ^ (row & 7);
        gload_lds16((const char*)(gbase + (long)row * rstride + cl * 8), (char*)lds + q * 16);
    }
}
// Read staged V tile: row in [0,256) (d), k-slice = ks*32 + hi*8 (n within 64).
__device__ inline sh8 ldsV(const bf16* lds, int row, int ks, int hi) {
    return *(const sh8*)((const char*)lds + row * 128 + (((ks * 4 + hi) ^ (row & 7)) << 4));
}

// Swizzled P strip: [4 waves][32 rows][64 cols] bf16, rows 128B, chunk^=(row&7).
__device__ inline void pstore(bf16* P, int w, int row, int col, bf16 v) {
    int c16 = (col >> 3) ^ (row & 7);
    ((bf16*)((char*)P + w * 4096 + row * 128 + c16 * 16))[col & 7] = v;
}
__device__ inline sh8 pload(const bf16* P, int w, int row, int chunk) {
    return *(const sh8*)((const char*)P + w * 4096 + row * 128 + ((chunk ^ (row & 7)) << 4));
}

// ---------------------------------------------------------------------------
// bf16 MFMA GEMM
// ---------------------------------------------------------------------------
template<int BN>
__global__ __launch_bounds__(256, 4)
void gemm_bf16(const bf16* __restrict__ A, int lda,
               const bf16* __restrict__ Bt, int ldb, long wstride,
               float* C, int ldc, bf16* Cbf,
               int M, int N, int K, int Kc,
               float alpha, const float* __restrict__ bias, long bstride,
               const float* res, int ldres, int flags,
               const bf16* __restrict__ zerobuf)
{
    constexpr int MI  = (BN == 128) ? 4 : 2;
    constexpr int BCH = BN * 8 / 256;
    __shared__ char smem[16384 + BN * 128];
    char* sA = smem;
    char* sB = smem + 16384;
    const int tid  = threadIdx.x;
    const int lane = tid & 63;
    const int lo   = lane & 15, hi = lane >> 4;
    const int wid  = tid >> 6;
    const int rowbase = (BN == 128) ? (wid >> 1) * 64 : wid * 32;
    const int colbase = (BN == 128) ? (wid & 1) * 64 : 0;
    const int bm = blockIdx.y * 128, bn = blockIdx.x * BN;

    const int eid = (blockIdx.y * 128) >> 11;
    const bf16* Bte = Bt + (long)eid * wstride;
    const float* biase = bias ? (bias + (long)eid * bstride) : nullptr;

    const int kbeg = blockIdx.z * Kc;
    const int kend = min(K, kbeg + Kc);

    fx4 acc[MI][4] = {};

    for (int k0 = kbeg; k0 < kend; k0 += 64) {
        #pragma unroll
        for (int i = 0; i < 4; ++i) {
            int id  = i * 256 + tid;
            int row = id >> 3;
            int c   = (id & 7) ^ (row & 7);
            int gk  = k0 + c * 8;
            const bf16* gp = (gk < kend) ? (A + (long)(bm + row) * lda + gk) : zerobuf;
            gload_lds16(gp, sA + id * 16);
        }
        #pragma unroll
        for (int i = 0; i < BCH; ++i) {
            int id  = i * 256 + tid;
            int row = id >> 3;
            int c   = (id & 7) ^ (row & 7);
            int gk  = k0 + c * 8;
            const bf16* gp = (gk < kend && bn + row < N) ? (Bte + (long)(bn + row) * ldb + gk)
                                                         : zerobuf;
            gload_lds16(gp, sB + id * 16);
        }
        asm volatile("s_waitcnt vmcnt(0)" ::: "memory");
        __syncthreads();

        #pragma unroll
        for (int kk = 0; kk < 2; ++kk) {
            const int ko = kk * 32 + hi * 8;
            sh8 af[MI], bfr[4];
            #pragma unroll
            for (int i = 0; i < MI; ++i) {
                int row = rowbase + i * 16 + lo;
                int off = (row * 128 + ko * 2) ^ ((row & 7) << 4);
                af[i] = *(const sh8*)(sA + off);
            }
            #pragma unroll
            for (int j = 0; j < 4; ++j) {
                int row = colbase + j * 16 + lo;
                int off = (row * 128 + ko * 2) ^ ((row & 7) << 4);
                bfr[j] = *(const sh8*)(sB + off);
            }
            #pragma unroll
            for (int i = 0; i < MI; ++i)
                #pragma unroll
                for (int j = 0; j < 4; ++j)
                    acc[i][j] = MFMA16(af[i], bfr[j], acc[i][j], 0, 0, 0);
        }
        __syncthreads();
    }

    const bool z0 = (blockIdx.z == 0);
    #pragma unroll
    for (int j = 0; j < 4; ++j) {
        int col = bn + colbase + j * 16 + lo;
        if (col >= N) continue;
        #pragma unroll
        for (int i = 0; i < MI; ++i) {
            #pragma unroll
            for (int r = 0; r < 4; ++r) {
                int row = bm + rowbase + i * 16 + hi * 4 + r;
                float v = alpha * acc[i][j][r];
                if (z0) {
                    if (biase) v += biase[col];
                    if (res)   v += res[(long)row * ldres + col];
                }
                if (flags & GF_RELU) v = fmaxf(v, 0.f);
                long idx = (long)row * ldc + col;
                if (flags & GF_ATOMIC) atomicAdd(&C[idx], v);
                else {
                    if (C)   C[idx] = v;
                    if (Cbf) Cbf[idx] = __float2bfloat16(v);
                }
            }
        }
    }
}

// ---------------------------------------------------------------------------
// Flash MHA (unstaged: K/V are L2-resident; padded Plds).
// ---------------------------------------------------------------------------
__global__ __launch_bounds__(256, 4)
void flash_mha(const bf16* __restrict__ qkv, const bf16* __restrict__ vT,
               bf16* __restrict__ obuf)
{
    const int e = blockIdx.z, h = blockIdx.y;
    const int n0 = blockIdx.x * 64;
    const int tid = threadIdx.x, lane = tid & 63, w = tid >> 6;
    const int lo = lane & 15, hi = lane >> 4;
    const float scaleH = 0.17677669529663687f;
    const bf16* qkv_e = qkv + (long)e * N_ * 768;
    const bf16* vT_eh = vT + ((long)e * D_ + h * 32) * N_;
    __shared__ bf16 Plds[4][16][72];

    sh8 qf = *(const sh8*)(qkv_e + (long)(n0 + w * 16 + lo) * 768 + h * 32 + hi * 8);

    float m[4], l[4];
    fx4 acc[2] = {};
    #pragma unroll
    for (int r = 0; r < 4; ++r) { m[r] = -INFINITY; l[r] = 0.f; }

    for (int kc = 0; kc < N_; kc += 64) {
        float sv[4][4], rmax[4], rsum[4];
        #pragma unroll
        for (int j = 0; j < 4; ++j) {
            sh8 kf = *(const sh8*)(qkv_e + (long)(kc + j * 16 + lo) * 768 + 256 + h * 32 + hi * 8);
            fx4 s = {};
            s = MFMA16(qf, kf, s, 0, 0, 0);
            #pragma unroll
            for (int r = 0; r < 4; ++r) sv[j][r] = s[r] * scaleH;
        }
        #pragma unroll
        for (int r = 0; r < 4; ++r)
            rmax[r] = fmaxf(fmaxf(sv[0][r], sv[1][r]), fmaxf(sv[2][r], sv[3][r]));
        #pragma unroll
        for (int d = 1; d < 16; d <<= 1)
            #pragma unroll
            for (int r = 0; r < 4; ++r) rmax[r] = fmaxf(rmax[r], __shfl_xor(rmax[r], d, 64));
        float sc[4];
        #pragma unroll
        for (int r = 0; r < 4; ++r) {
            float mn = fmaxf(m[r], rmax[r]);
            sc[r] = __expf(m[r] - mn);
            m[r] = mn; rsum[r] = 0.f;
        }
        #pragma unroll
        for (int j = 0; j < 4; ++j)
            #pragma unroll
            for (int r = 0; r < 4; ++r) {
                float p = __expf(sv[j][r] - m[r]);
                sv[j][r] = p; rsum[r] += p;
            }
        #pragma unroll
        for (int d = 1; d < 16; d <<= 1)
            #pragma unroll
            for (int r = 0; r < 4; ++r) rsum[r] += __shfl_xor(rsum[r], d, 64);
        #pragma unroll
        for (int r = 0; r < 4; ++r) l[r] = l[r] * sc[r] + rsum[r];
        #pragma unroll
        for (int j2 = 0; j2 < 2; ++j2)
            #pragma unroll
            for (int r = 0; r < 4; ++r) acc[j2][r] *= sc[r];
        #pragma unroll
        for (int j = 0; j < 4; ++j)
            #pragma unroll
            for (int r = 0; r < 4; ++r)
                Plds[w][hi * 4 + r][j * 16 + lo] = __float2bfloat16(sv[j][r]);
        asm volatile("s_waitcnt lgkmcnt(0)" ::: "memory");
        __builtin_amdgcn_sched_barrier(0);
        __builtin_amdgcn_s_setprio(1);
        #pragma unroll
        for (int ks = 0; ks < 2; ++ks) {
            sh8 pa = *(const sh8*)(&Plds[w][lo][ks * 32 + hi * 8]);
            #pragma unroll
            for (int j2 = 0; j2 < 2; ++j2) {
                sh8 vb = *(const sh8*)(vT_eh + (long)(j2 * 16 + lo) * N_ + kc + ks * 32 + hi * 8);
                acc[j2] = MFMA16(pa, vb, acc[j2], 0, 0, 0);
            }
        }
        __builtin_amdgcn_s_setprio(0);
    }
    #pragma unroll
    for (int j2 = 0; j2 < 2; ++j2)
        #pragma unroll
        for (int r = 0; r < 4; ++r) {
            long row = (long)e * N_ + n0 + w * 16 + hi * 4 + r;
            obuf[row * D_ + h * 32 + j2 * 16 + lo] = __float2bfloat16(acc[j2][r] / l[r]);
        }
}

// ---------------------------------------------------------------------------
// Flash cross-attention: grid (N/64, CCH, E). K + V tiles staged in LDS.
// ---------------------------------------------------------------------------
__global__ __launch_bounds__(256, 2)
void flash_cross(const bf16* __restrict__ tok, const bf16* __restrict__ tokT,
                 bf16* __restrict__ Opart, float2* __restrict__ ml)
{
    const int e = blockIdx.z, ch = blockIdx.y;
    const int n0 = blockIdx.x * 64;
    const int tid = threadIdx.x, lane = tid & 63, w = tid >> 6;
    const int lo = lane & 15, hi = lane >> 4;
    const float scaleD = 1.0f / 16.0f;
    __shared__ bf16 Kt[64 * 256];
    __shared__ bf16 Vt[256 * 64];
    __shared__ bf16 Plds[4][16][72];

    sh8 qf[8];
    {
        const bf16* qr = tok + ((long)e * N_ + n0 + w * 16 + lo) * D_;
        #pragma unroll
        for (int ks = 0; ks < 8; ++ks) qf[ks] = *(const sh8*)(qr + ks * 32 + hi * 8);
    }
    float m[4], l[4];
    fx4 acc[16] = {};
    #pragma unroll
    for (int r = 0; r < 4; ++r) { m[r] = -INFINITY; l[r] = 0.f; }

    for (int kc = ch * 768; kc < ch * 768 + 768; kc += 64) {
        const int seg = kc >> 11;
        const int src = (seg < e) ? seg : seg + 1;
        const int rowb = kc & 2047;
        stage_k64(tok + ((long)src * N_ + rowb) * D_, Kt, tid);
        stage_v64(tokT + (long)src * D_ * N_ + rowb, N_, Vt, tid);
        asm volatile("s_waitcnt vmcnt(0)" ::: "memory");
        __syncthreads();

        float sv[4][4], rmax[4], rsum[4];
        __builtin_amdgcn_s_setprio(1);
        #pragma unroll
        for (int j = 0; j < 4; ++j) {
            int krow = j * 16 + lo;
            fx4 s = {};
            #pragma unroll
            for (int ks = 0; ks < 8; ++ks) {
                sh8 kf = ldsK(Kt, krow, ks, hi);
                s = MFMA16(qf[ks], kf, s, 0, 0, 0);
            }
            #pragma unroll
            for (int r = 0; r < 4; ++r) sv[j][r] = s[r] * scaleD;
        }
        __builtin_amdgcn_s_setprio(0);
        #pragma unroll
        for (int r = 0; r < 4; ++r)
            rmax[r] = fmaxf(fmaxf(sv[0][r], sv[1][r]), fmaxf(sv[2][r], sv[3][r]));
        #pragma unroll
        for (int d = 1; d < 16; d <<= 1)
            #pragma unroll
            for (int r = 0; r < 4; ++r) rmax[r] = fmaxf(rmax[r], __shfl_xor(rmax[r], d, 64));
        float sc[4];
        #pragma unroll
        for (int r = 0; r < 4; ++r) {
            float mn = fmaxf(m[r], rmax[r]);
            sc[r] = __expf(m[r] - mn);
            m[r] = mn; rsum[r] = 0.f;
        }
        #pragma unroll
        for (int j = 0; j < 4; ++j)
            #pragma unroll
            for (int r = 0; r < 4; ++r) {
                float p = __expf(sv[j][r] - m[r]);
                sv[j][r] = p; rsum[r] += p;
            }
        #pragma unroll
        for (int d = 1; d < 16; d <<= 1)
            #pragma unroll
            for (int r = 0; r < 4; ++r) rsum[r] += __shfl_xor(rsum[r], d, 64);
        #pragma unroll
        for (int r = 0; r < 4; ++r) l[r] = l[r] * sc[r] + rsum[r];
        #pragma unroll
        for (int j2 = 0; j2 < 16; ++j2)
            #pragma unroll
            for (int r = 0; r < 4; ++r) acc[j2][r] *= sc[r];
        #pragma unroll
        for (int j = 0; j < 4; ++j)
            #pragma unroll
            for (int r = 0; r < 4; ++r)
                Plds[w][hi * 4 + r][j * 16 + lo] = __float2bfloat16(sv[j][r]);
        asm volatile("s_waitcnt lgkmcnt(0)" ::: "memory");
        __builtin_amdgcn_sched_barrier(0);
        __builtin_amdgcn_s_setprio(1);
        #pragma unroll
        for (int ks = 0; ks < 2; ++ks) {
            sh8 pa = *(const sh8*)(&Plds[w][lo][ks * 32 + hi * 8]);
            #pragma unroll
            for (int j2 = 0; j2 < 16; ++j2) {
                sh8 vb = ldsV(Vt, j2 * 16 + lo, ks, hi);
                acc[j2] = MFMA16(pa, vb, acc[j2], 0, 0, 0);
            }
        }
        __builtin_amdgcn_s_setprio(0);
        __syncthreads();
    }
    const long base = (long)ch * E_ * N_ + (long)e * N_ + n0 + w * 16;
    #pragma unroll
    for (int j2 = 0; j2 < 16; ++j2)
        #pragma unroll
        for (int r = 0; r < 4; ++r)
            Opart[(base + hi * 4 + r) * D_ + j2 * 16 + lo] = __float2bfloat16(acc[j2][r] / l[r]);
    if (lo == 0) {
        #pragma unroll
        for (int r = 0; r < 4; ++r) {
            float2 t; t.x = m[r]; t.y = l[r];
            ml[base + hi * 4 + r] = t;
        }
    }
}

// Merge chunk-partials + token residual.
__global__ void cross_merge(const bf16* __restrict__ Opart, const float2* __restrict__ ml,
                            const float* __restrict__ tokens,
                            float* __restrict__ x0f, bf16* __restrict__ x0bf)
{
    long row = blockIdx.x; int d = threadIdx.x;
    float2 v[CCH];
    float mx = -INFINITY;
    #pragma unroll
    for (int i = 0; i < CCH; ++i) { v[i] = ml[(long)i * E_ * N_ + row]; mx = fmaxf(mx, v[i].x); }
    float L = 0.f, o = 0.f;
    #pragma unroll
    for (int i = 0; i < CCH; ++i) {
        float wgt = v[i].y * __expf(v[i].x - mx);
        L += wgt;
        o += wgt * __bfloat162float(Opart[((long)i * E_ * N_ + row) * D_ + d]);
    }
    float val = tokens[row * D_ + d] + o / L;
    x0f[row * D_ + d] = val;
    x0bf[row * D_ + d] = __float2bfloat16(val);
}

// ---------------------------------------------------------------------------
// ret_flash (R11): per (q-tile, layer, e*2+mhalf). K + V staged. Deferred l-reduce.
// ---------------------------------------------------------------------------
__global__ __launch_bounds__(256, 2)
void ret_flash(const bf16* __restrict__ x2b, const bf16* __restrict__ memb,
               const bf16* __restrict__ maggT, bf16* __restrict__ OmemH,
               float* __restrict__ rsH)
{
    const int li = blockIdx.y;
    const int e = blockIdx.z >> 1, mh = blockIdx.z & 1;
    const int n0 = blockIdx.x * 64;
    const int tid = threadIdx.x, lane = tid & 63, w = tid >> 6;
    const int lo = lane & 15, hi = lane >> 4;
    const float scaleD = 1.0f / 16.0f;
    __shared__ bf16 Kt[64 * 256];
    __shared__ bf16 Vt[256 * 64];
    __shared__ bf16 Plds[4][16][72];

    sh8 qf[8];
    {
        const bf16* qr = x2b + ((long)e * N_ + n0 + w * 16 + lo) * D_;
        #pragma unroll
        for (int ks = 0; ks < 8; ++ks) qf[ks] = *(const sh8*)(qr + ks * 32 + hi * 8);
    }
    float l[4] = {0.f, 0.f, 0.f, 0.f};
    fx4 acc[16] = {};
    const bf16* Kl = memb + (long)li * M_ * D_;
    const bf16* Vl = maggT + (long)li * D_ * M_;
    const int mbase = mh * 2048;

    for (int t = 0; t < 32; ++t) {
        const int m0 = mbase + t * 64;
        stage_k64(Kl + (long)m0 * D_, Kt, tid);
        stage_v64(Vl + m0, M_, Vt, tid);
        asm volatile("s_waitcnt vmcnt(0)" ::: "memory");
        __syncthreads();

        __builtin_amdgcn_s_setprio(1);
        #pragma unroll
        for (int j = 0; j < 4; ++j) {
            int krow = j * 16 + lo;
            fx4 s = {};
            #pragma unroll
            for (int ks = 0; ks < 8; ++ks) {
                sh8 kf = ldsK(Kt, krow, ks, hi);
                s = MFMA16(qf[ks], kf, s, 0, 0, 0);
            }
            #pragma unroll
            for (int r = 0; r < 4; ++r) {
                float p = __expf(s[r] * scaleD);
                l[r] += p;
                Plds[w][hi * 4 + r][j * 16 + lo] = __float2bfloat16(p);
            }
        }
        __builtin_amdgcn_s_setprio(0);
        asm volatile("s_waitcnt lgkmcnt(0)" ::: "memory");
        __builtin_amdgcn_sched_barrier(0);
        __builtin_amdgcn_s_setprio(1);
        #pragma unroll
        for (int ks = 0; ks < 2; ++ks) {
            sh8 pa = *(const sh8*)(&Plds[w][lo][ks * 32 + hi * 8]);
            #pragma unroll
            for (int j2 = 0; j2 < 16; ++j2) {
                sh8 vb = ldsV(Vt, j2 * 16 + lo, ks, hi);
                acc[j2] = MFMA16(pa, vb, acc[j2], 0, 0, 0);
            }
        }
        __builtin_amdgcn_s_setprio(0);
        __syncthreads();
    }
    #pragma unroll
    for (int d = 1; d < 16; d <<= 1)
        #pragma unroll
        for (int r = 0; r < 4; ++r) l[r] += __shfl_xor(l[r], d, 64);

    const long rowb = ((long)(mh * 12 + e * L_ + li)) * N_ + n0 + w * 16;
    #pragma unroll
    for (int j2 = 0; j2 < 16; ++j2)
        #pragma unroll
        for (int r = 0; r < 4; ++r)
            OmemH[(rowb + hi * 4 + r) * D_ + j2 * 16 + lo] = __float2bfloat16(acc[j2][r]);
    if (lo == 0) {
        #pragma unroll
        for (int r = 0; r < 4; ++r)
            rsH[rowb + hi * 4 + r] = l[r];
    }
}

// rsinv[i] = 1/(rsH[i] + rsH[12N + i])  for i in [0, 12N)
__global__ void rsinv_kernel(const float* __restrict__ rsH, float* __restrict__ rsinv) {
    long i = (long)blockIdx.x * 256 + threadIdx.x;
    if (i < (long)12 * N_)
        rsinv[i] = 1.0f / (rsH[i] + rsH[(long)12 * N_ + i]);
}

// ---------------------------------------------------------------------------
// upd_flash v3: 256 thr, 4 waves × 32 m-rows (2 output fragments per wave),
// swizzled unpadded Plds [4][32][64] -> LDS total exactly 80KB -> 2 blocks/CU.
// __launch_bounds__(256,2) caps VGPR at 256 (v2 measured 204, fits).
// grid (M/128, L, E). updpart[e][l][m][d] = (exp(mem@x2^T/16)*rsinv) @ x2.
// ---------------------------------------------------------------------------
__global__ __launch_bounds__(256, 2)
void upd_flash(const bf16* __restrict__ x2b, const bf16* __restrict__ memb,
               const bf16* __restrict__ x2T, const float* __restrict__ rsinv,
               bf16* __restrict__ updpart)
{
    const int li = blockIdx.y, e = blockIdx.z;
    const int m0 = blockIdx.x * 128;
    const int tid = threadIdx.x, lane = tid & 63, w = tid >> 6;
    const int lo = lane & 15, hi = lane >> 4;
    const float scaleD = 1.0f / 16.0f;
    __shared__ bf16 Kt[64 * 256];       // 32 KB
    __shared__ bf16 Vt[256 * 64];       // 32 KB
    __shared__ bf16 Plds[4 * 32 * 64];  // 16 KB, swizzled

    sh8 qf0[8], qf1[8];
    {
        const bf16* qr0 = memb + (long)li * M_ * D_ + (long)(m0 + w * 32 + lo) * D_;
        const bf16* qr1 = qr0 + 16 * D_;
        #pragma unroll
        for (int ks = 0; ks < 8; ++ks) {
            qf0[ks] = *(const sh8*)(qr0 + ks * 32 + hi * 8);
            qf1[ks] = *(const sh8*)(qr1 + ks * 32 + hi * 8);
        }
    }
    fx4 acc0[16] = {}, acc1[16] = {};
    const float* rse = rsinv + (long)(e * L_ + li) * N_;
    const bf16* x2Te = x2T + (long)e * D_ * N_;

    for (int t = 0; t < 32; ++t) {
        const int n0 = t * 64;
        stage_k64(x2b + ((long)e * N_ + n0) * D_, Kt, tid);
        stage_v64(x2Te + n0, N_, Vt, tid);
        float rinv[4];
        #pragma unroll
        for (int j = 0; j < 4; ++j) rinv[j] = rse[n0 + j * 16 + lo];
        asm volatile("s_waitcnt vmcnt(0)" ::: "memory");
        __syncthreads();

        __builtin_amdgcn_s_setprio(1);
        #pragma unroll
        for (int j = 0; j < 4; ++j) {
            int krow = j * 16 + lo;
            fx4 s0 = {}, s1 = {};
            #pragma unroll
            for (int ks = 0; ks < 8; ++ks) {
                sh8 kf = ldsK(Kt, krow, ks, hi);
                s0 = MFMA16(qf0[ks], kf, s0, 0, 0, 0);
                s1 = MFMA16(qf1[ks], kf, s1, 0, 0, 0);
            }
            #pragma unroll
            for (int r = 0; r < 4; ++r) {
                float p0 = __expf(s0[r] * scaleD) * rinv[j];
                float p1 = __expf(s1[r] * scaleD) * rinv[j];
                pstore(Plds, w, hi * 4 + r,      j * 16 + lo, __float2bfloat16(p0));
                pstore(Plds, w, 16 + hi * 4 + r, j * 16 + lo, __float2bfloat16(p1));
            }
        }
        __builtin_amdgcn_s_setprio(0);
        asm volatile("s_waitcnt lgkmcnt(0)" ::: "memory");
        __builtin_amdgcn_sched_barrier(0);
        __builtin_amdgcn_s_setprio(1);
        #pragma unroll
        for (int ks = 0; ks < 2; ++ks) {
            sh8 pa0 = pload(Plds, w, lo,      ks * 4 + hi);
            sh8 pa1 = pload(Plds, w, 16 + lo, ks * 4 + hi);
            #pragma unroll
            for (int j2 = 0; j2 < 16; ++j2) {
                sh8 vb = ldsV(Vt, j2 * 16 + lo, ks, hi);
                acc0[j2] = MFMA16(pa0, vb, acc0[j2], 0, 0, 0);
                acc1[j2] = MFMA16(pa1, vb, acc1[j2], 0, 0, 0);
            }
        }
        __builtin_amdgcn_s_setprio(0);
        __syncthreads();
    }
    const long mrow = ((long)(e * L_ + li)) * M_ + m0 + w * 32;
    #pragma unroll
    for (int j2 = 0; j2 < 16; ++j2)
        #pragma unroll
        for (int r = 0; r < 4; ++r) {
            updpart[(mrow + hi * 4 + r) * D_ + j2 * 16 + lo]      = __float2bfloat16(acc0[j2][r]);
            updpart[(mrow + 16 + hi * 4 + r) * D_ + j2 * 16 + lo] = __float2bfloat16(acc1[j2][r]);
        }
}

// xfinal[e,n] += sum_l (O0+O1)*rsinv + agg_b
__global__ void retscale(const bf16* __restrict__ OmemH, const float* __restrict__ rsinv,
                         const float* __restrict__ aggb, float* __restrict__ xfinal)
{
    long row = blockIdx.x; int d = threadIdx.x;
    int e = (int)(row >> 11); long n = row & 2047;
    float s = aggb[d];
    #pragma unroll
    for (int li = 0; li < L_; ++li) {
        long r0 = ((long)(e * L_ + li)) * N_ + n;
        long r1 = ((long)(12 + e * L_ + li)) * N_ + n;
        float o = __bfloat162float(OmemH[r0 * D_ + d]) + __bfloat162float(OmemH[r1 * D_ + d]);
        s += o * rsinv[r0];
    }
    xfinal[row * D_ + d] += s;
}

// LayerNorm over D=256, per-expert weights (expert = row>>11). f32 + bf16 out.
__global__ void layernorm_rows(const float* __restrict__ X, const float* __restrict__ g,
                               const float* __restrict__ b, float* __restrict__ out,
                               bf16* __restrict__ outbf)
{
    __shared__ float red[256];
    int row = blockIdx.x, t = threadIdx.x;
    int e = row >> 11;
    float v = X[(long)row * 256 + t];
    red[t] = v; __syncthreads();
    for (int s = 128; s > 0; s >>= 1) { if (t < s) red[t] += red[t + s]; __syncthreads(); }
    float mu = red[0] * (1.0f / 256.0f); __syncthreads();
    float d = v - mu;
    red[t] = d * d; __syncthreads();
    for (int s = 128; s > 0; s >>= 1) { if (t < s) red[t] += red[t + s]; __syncthreads(); }
    float var = red[0] * (1.0f / 256.0f);
    float o = d * rsqrtf(var + EPS_) * g[e * 256 + t] + b[e * 256 + t];
    out[(long)row * 256 + t] = o;
    outbf[(long)row * 256 + t] = __float2bfloat16(o);
}

__global__ void cvt_bf16(const float* __restrict__ in, bf16* __restrict__ out, long n) {
    long i = ((long)blockIdx.x * 256 + threadIdx.x) * 4;
    if (i < n) {
        float4 v = *(const float4*)(in + i);
        out[i + 0] = __float2bfloat16(v.x);
        out[i + 1] = __float2bfloat16(v.y);
        out[i + 2] = __float2bfloat16(v.z);
        out[i + 3] = __float2bfloat16(v.w);
    }
}

__device__ inline float ldf(const float* p) { return *p; }
__device__ inline float ldf(const bf16* p)  { return __bfloat162float(*p); }

template<typename T>
__global__ void transpose_bf16(const T* __restrict__ in, bf16* __restrict__ out,
                               int R, int C, int ldin, int ldout) {
    __shared__ float t[64][65];
    int tx = threadIdx.x & 63, ty = threadIdx.x >> 6;
    int r0 = blockIdx.y * 64, c0 = blockIdx.x * 64;
    #pragma unroll
    for (int i = 0; i < 16; ++i) {
        int r = ty + i * 4;
        t[r][tx] = ldf(&in[(long)(r0 + r) * ldin + (c0 + tx)]);
    }
    __syncthreads();
    #pragma unroll
    for (int i = 0; i < 16; ++i) {
        int c = ty + i * 4;
        out[(long)(c0 + c) * ldout + (r0 + tx)] = __float2bfloat16(t[tx][c]);
    }
}

// out_mem = 0.9*mem + 0.1*sum_e updpart[e]
__global__ void mem_update(const float4* __restrict__ mem, const bf16* __restrict__ updpart,
                           float4* __restrict__ out) {
    long i = (long)blockIdx.x * 256 + threadIdx.x;
    const long LMD = (long)L_ * M_ * D_;
    if (i < LMD / 4) {
        float4 a = mem[i];
        float s0 = 0.f, s1 = 0.f, s2 = 0.f, s3 = 0.f;
        #pragma unroll
        for (int e = 0; e < E_; ++e) {
            const bf16* u = updpart + e * LMD + i * 4;
            s0 += __bfloat162float(u[0]);
            s1 += __bfloat162float(u[1]);
            s2 += __bfloat162float(u[2]);
            s3 += __bfloat162float(u[3]);
        }
        float4 r;
        r.x = (1.0f - GAMMA_) * a.x + GAMMA_ * s0;
        r.y = (1.0f - GAMMA_) * a.y + GAMMA_ * s1;
        r.z = (1.0f - GAMMA_) * a.z + GAMMA_ * s2;
        r.w = (1.0f - GAMMA_) * a.w + GAMMA_ * s3;
        out[i] = r;
    }
}

__global__ void pool_partial(const float* __restrict__ xf, float* __restrict__ pooled) {
    int e = blockIdx.x, chunk = blockIdx.y, t = threadIdx.x;
    float s = 0.f;
    int n0 = chunk * (N_ / 16);
    for (int n = n0; n < n0 + N_ / 16; ++n)
        s += xf[((long)e * N_ + n) * D_ + t];
    atomicAdd(&pooled[e * D_ + t], s * (1.0f / (float)N_));
}

__global__ void gate_kernel(const float* __restrict__ pooled, const float* __restrict__ gg,
                            float* __restrict__ out_gate, float* __restrict__ ws_gate) {
    __shared__ float red[256];
    __shared__ float logits[4];
    int t = threadIdx.x;
    for (int e = 0; e < 4; ++e) {
        red[t] = pooled[e * 256 + t] * gg[t];
        __syncthreads();
        for (int s = 128; s > 0; s >>= 1) { if (t < s) red[t] += red[t + s]; __syncthreads(); }
        if (t == 0) logits[e] = red[0];
        __syncthreads();
    }
    if (t == 0) {
        float mm = fmaxf(fmaxf(logits[0], logits[1]), fmaxf(logits[2], logits[3]));
        float g[4]; float s = 0.f;
        for (int e = 0; e < 4; ++e) { g[e] = __expf(logits[e] - mm); s += g[e]; }
        for (int e = 0; e < 4; ++e) {
            float w = g[e] / s;
            out_gate[e] = w;
            ws_gate[e] = w;
        }
    }
}

__global__ void fuse_kernel(const float* __restrict__ xf, const float* __restrict__ g4,
                            float* __restrict__ out) {
    long i = (long)blockIdx.x * 256 + threadIdx.x;
    const long ND = (long)N_ * D_;
    if (i < ND)
        out[i] = g4[0] * xf[i] + g4[1] * xf[ND + i] + g4[2] * xf[2 * ND + i] + g4[3] * xf[3 * ND + i];
}

// ---------------------------------------------------------------------------

static void gemm(hipStream_t s, int BN, const bf16* A, int lda, const bf16* Bt, int ldb,
                 long wstride, float* C, int ldc, bf16* Cbf, int M, int N, int K, int Kc,
                 float alpha, const float* bias, long bstride, const float* res, int ldres,
                 int flags, const bf16* zb) {
    dim3 g((N + BN - 1) / BN, (M + 127) / 128, (K + Kc - 1) / Kc);
    if (BN == 128)
        gemm_bf16<128><<<g, dim3(256), 0, s>>>(A, lda, Bt, ldb, wstride, C, ldc, Cbf, M, N, K, Kc,
                                               alpha, bias, bstride, res, ldres, flags, zb);
    else
        gemm_bf16<64><<<g, dim3(256), 0, s>>>(A, lda, Bt, ldb, wstride, C, ldc, Cbf, M, N, K, Kc,
                                              alpha, bias, bstride, res, ldres, flags, zb);
}

static void transposeF(hipStream_t s, const float* in, bf16* out, int R, int C, int ldin, int ldout) {
    transpose_bf16<float><<<dim3(C / 64, R / 64), dim3(256), 0, s>>>(in, out, R, C, ldin, ldout);
}
static void transposeB(hipStream_t s, const bf16* in, bf16* out, int R, int C, int ldin, int ldout) {
    transpose_bf16<bf16><<<dim3(C / 64, R / 64), dim3(256), 0, s>>>(in, out, R, C, ldin, ldout);
}
static void convert(hipStream_t s, const float* in, bf16* out, long n) {
    cvt_bf16<<<dim3((unsigned)((n / 4 + 255) / 256)), dim3(256), 0, s>>>(in, out, n);
}

extern "C" void kernel_launch(void* const* d_in, const int* in_sizes, int n_in,
                              void* d_out, int out_size, void* d_ws, size_t ws_size,
                              hipStream_t stream) {
    const float* tokens    = (const float*)d_in[0];
    const float* memories  = (const float*)d_in[1];
    const float* in_proj_w = (const float*)d_in[2];
    const float* in_proj_b = (const float*)d_in[3];
    const float* out_w     = (const float*)d_in[4];
    const float* out_b     = (const float*)d_in[5];
    const float* lin1_w    = (const float*)d_in[6];
    const float* lin1_b    = (const float*)d_in[7];
    const float* lin2_w    = (const float*)d_in[8];
    const float* lin2_b    = (const float*)d_in[9];
    const float* ln1_w     = (const float*)d_in[10];
    const float* ln1_b     = (const float*)d_in[11];
    const float* ln2_w     = (const float*)d_in[12];
    const float* ln2_b     = (const float*)d_in[13];
    const float* agg_w     = (const float*)d_in[14];
    const float* agg_b     = (const float*)d_in[15];
    const float* gg        = (const float*)d_in[16];

    char* p = (char*)d_ws;
    auto alloc = [&](size_t bytes) { char* r = p; p += (bytes + 255) & ~(size_t)255; return r; };

    // regionA (32MB), time-shared: Opart(cross) -> hid_all(FFN) -> OmemH(mem, bf16 halves)
    char*  regionA = alloc((size_t)32 * 1024 * 1024);
    bf16*  Opart   = (bf16*)regionA;                    // [8][E*N][256] bf16 = 32MB
    bf16*  hid_all = (bf16*)regionA;                    // [8192][2048] bf16 = 32MB
    bf16*  OmemH   = (bf16*)regionA;                    // [2][12][2048][256] bf16 = 25.2MB

    // regionB (32MB), time-shared: qkv|vT|obuf (MHA) -> updpart (mem)
    char*  regionB = alloc((size_t)32 * 1024 * 1024);
    bf16*  qkv_bf  = (bf16*)regionB;                              // 12.58MB
    bf16*  vT_bf   = (bf16*)(regionB + 12582912);                 // 4.19MB
    bf16*  obuf_bf = (bf16*)(regionB + 12582912 + 4194304);       // 4.19MB
    bf16*  updpart = (bf16*)regionB;                              // [4][3][4096][256] bf16 = 25.2MB

    float* xfinal  = (float*)alloc((size_t)E_ * N_ * D_ * 4);
    bf16*  x2_bf   = (bf16*)alloc((size_t)E_ * N_ * D_ * 2);
    bf16*  x2T_bf  = (bf16*)alloc((size_t)E_ * D_ * N_ * 2);
    float* x0f     = (float*)alloc((size_t)E_ * N_ * D_ * 4);
    bf16*  x0bf    = (bf16*)alloc((size_t)E_ * N_ * D_ * 2);
    float* ybuf    = (float*)alloc((size_t)E_ * N_ * D_ * 4);
    bf16*  tok_bf  = (bf16*)alloc((size_t)E_ * N_ * D_ * 2);
    bf16*  tokT_bf = (bf16*)alloc((size_t)E_ * D_ * N_ * 2);
    bf16*  mem_bf  = (bf16*)alloc((size_t)L_ * M_ * D_ * 2);
    bf16*  maggT   = (bf16*)alloc((size_t)L_ * D_ * M_ * 2);
    float2* mlbuf  = (float2*)alloc((size_t)CCH * E_ * N_ * sizeof(float2));
    float* rsH     = (float*)alloc((size_t)2 * 12 * N_ * 4);
    float* rsinv   = (float*)alloc((size_t)12 * N_ * 4);
    bf16*  ipw_bf  = (bf16*)alloc((size_t)E_ * 3 * D_ * D_ * 2);
    bf16*  outw_bf = (bf16*)alloc((size_t)E_ * D_ * D_ * 2);
    bf16*  l1w_bf  = (bf16*)alloc((size_t)E_ * F_ * D_ * 2);
    bf16*  l2w_bf  = (bf16*)alloc((size_t)E_ * D_ * F_ * 2);
    bf16*  aggw_bf = (bf16*)alloc((size_t)D_ * 3 * D_ * 2);
    float* pooled  = (float*)alloc(1024 * 4);
    float* gatebuf = (float*)alloc(64);
    bf16*  zerobuf = (bf16*)alloc(64);

    float* x1f  = x0f;
    bf16*  x1bf = x0bf;

    float* out_fused = (float*)d_out;
    float* out_gate  = out_fused + (long)N_ * D_;
    float* out_mem   = out_gate + E_;

    hipMemsetAsync(zerobuf, 0, 64, stream);
    hipMemsetAsync(pooled, 0, 1024 * 4, stream);

    // one-time conversions / transposes
    convert(stream, tokens, tok_bf, (long)E_ * N_ * D_);
    convert(stream, memories, mem_bf, (long)L_ * M_ * D_);
    convert(stream, in_proj_w, ipw_bf, (long)E_ * 3 * D_ * D_);
    convert(stream, out_w, outw_bf, (long)E_ * D_ * D_);
    convert(stream, lin1_w, l1w_bf, (long)E_ * F_ * D_);
    convert(stream, lin2_w, l2w_bf, (long)E_ * D_ * F_);
    convert(stream, agg_w, aggw_bf, (long)D_ * 3 * D_);
    for (int e = 0; e < E_; ++e)
        transposeF(stream, tokens + (long)e * N_ * D_, tokT_bf + (long)e * D_ * N_, N_, D_, D_, N_);
    // maggT_l = agg_w_l @ mem_l^T : [256, 4096]
    for (int l = 0; l < L_; ++l)
        gemm(stream, 128, aggw_bf + l * D_, 3 * D_, mem_bf + (long)l * M_ * D_, D_, 0,
             nullptr, M_, maggT + (long)l * D_ * M_, D_, M_, D_, D_,
             1.0f, nullptr, 0, nullptr, 0, 0, zerobuf);

    // ---- cross-expert attention ----
    flash_cross<<<dim3(N_ / 64, CCH, E_), dim3(256), 0, stream>>>(tok_bf, tokT_bf, Opart, mlbuf);
    cross_merge<<<dim3(E_ * N_), dim3(256), 0, stream>>>(Opart, mlbuf, tokens, x0f, x0bf);

    // ---- MHA (batched) ----
    gemm(stream, 128, x0bf, D_, ipw_bf, D_, (long)3 * D_ * D_,
         nullptr, 3 * D_, qkv_bf, E_ * N_, 3 * D_, D_, D_,
         1.0f, in_proj_b, 3 * D_, nullptr, 0, 0, zerobuf);
    for (int e = 0; e < E_; ++e)
        transposeB(stream, qkv_bf + (long)e * N_ * 3 * D_ + 2 * D_, vT_bf + (long)e * D_ * N_,
                   N_, D_, 3 * D_, N_);
    flash_mha<<<dim3(N_ / 64, H_, E_), dim3(256), 0, stream>>>(qkv_bf, vT_bf, obuf_bf);
    gemm(stream, 64, obuf_bf, D_, outw_bf, D_, (long)D_ * D_,
         ybuf, D_, nullptr, E_ * N_, D_, D_, D_,
         1.0f, out_b, D_, x0f, D_, 0, zerobuf);
    layernorm_rows<<<dim3(E_ * N_), dim3(256), 0, stream>>>(ybuf, ln1_w, ln1_b, x1f, x1bf);

    // ---- FFN (batched) ----
    gemm(stream, 128, x1bf, D_, l1w_bf, D_, (long)F_ * D_,
         nullptr, F_, hid_all, E_ * N_, F_, D_, D_,
         1.0f, lin1_b, F_, nullptr, 0, GF_RELU, zerobuf);
    hipMemsetAsync(ybuf, 0, (size_t)E_ * N_ * D_ * 4, stream);
    gemm(stream, 64, hid_all, F_, l2w_bf, F_, (long)D_ * F_,
         ybuf, D_, nullptr, E_ * N_, D_, F_, 512,
         1.0f, lin2_b, D_, x1f, D_, GF_ATOMIC, zerobuf);
    layernorm_rows<<<dim3(E_ * N_), dim3(256), 0, stream>>>(ybuf, ln2_w, ln2_b, xfinal, x2_bf);
    for (int e = 0; e < E_; ++e)
        transposeF(stream, xfinal + (long)e * N_ * D_, x2T_bf + (long)e * D_ * N_, N_, D_, D_, N_);

    // ---- memory read/write (flash, no-max softmax, store-only epilogues) ----
    ret_flash<<<dim3(N_ / 64, L_, E_ * 2), dim3(256), 0, stream>>>(x2_bf, mem_bf, maggT, OmemH, rsH);
    rsinv_kernel<<<dim3((12 * N_ + 255) / 256), dim3(256), 0, stream>>>(rsH, rsinv);
    upd_flash<<<dim3(M_ / 128, L_, E_), dim3(256), 0, stream>>>(x2_bf, mem_bf, x2T_bf, rsinv, updpart);
    retscale<<<dim3(E_ * N_), dim3(256), 0, stream>>>(OmemH, rsinv, agg_b, xfinal);

    mem_update<<<dim3(L_ * M_ * D_ / 4 / 256), dim3(256), 0, stream>>>(
        (const float4*)memories, updpart, (float4*)out_mem);
    pool_partial<<<dim3(E_, 16), dim3(256), 0, stream>>>(xfinal, pooled);
    gate_kernel<<<dim3(1), dim3(256), 0, stream>>>(pooled, gg, out_gate, gatebuf);
    fuse_kernel<<<dim3((N_ * D_ + 255) / 256), dim3(256), 0, stream>>>(xfinal, gatebuf, out_fused);
}

// Round 14
// 839.125 us; speedup vs baseline: 1.1056x; 1.0828x over previous
//
#include <hip/hip_runtime.h>
#include <hip/hip_bf16.h>
#include <math.h>

#define E_ 4
#define N_ 2048
#define D_ 256
#define H_ 8
#define F_ 2048
#define M_ 4096
#define L_ 3
#define GAMMA_ 0.1f
#define EPS_ 1e-5f
#define CCH 8   // cross-attention key chunks

#define GF_ATOMIC 1
#define GF_RELU   2

typedef __attribute__((ext_vector_type(8))) short  sh8;
typedef __attribute__((ext_vector_type(4))) float  fx4;
typedef __hip_bfloat16 bf16;

#define MFMA16 __builtin_amdgcn_mfma_f32_16x16x32_bf16

__device__ inline void gload_lds16(const void* g, void* l) {
    __builtin_amdgcn_global_load_lds((const __attribute__((address_space(1))) void*)g,
                                     (__attribute__((address_space(3))) void*)l, 16, 0, 0);
}

// Stage a [64][256] bf16 tile (row stride 512B) into LDS, XOR-swizzled source.
__device__ inline void stage_k64(const bf16* __restrict__ gbase, bf16* lds, int tid) {
    #pragma unroll
    for (int i = 0; i < 8; ++i) {
        int q = i * 256 + tid;
        int row = q >> 5, cst = q & 31;
        int cl = cst ^ (row & 7);
        gload_lds16((const char*)gbase + row * 512 + cl * 16, (char*)lds + q * 16);
    }
}
// Read staged K tile: row, k-slice = ks*32 + hi*8 elements.
__device__ inline sh8 ldsK(const bf16* lds, int row, int ks, int hi) {
    return *(const sh8*)((const char*)lds + row * 512 + (((ks * 4 + hi) ^ (row & 7)) << 4));
}

// Stage a [256][64] bf16 tile (d-major; source row stride = rstride elems) into LDS.
__device__ inline void stage_v64(const bf16* __restrict__ gbase, long rstride, bf16* lds, int tid) {
    #pragma unroll
    for (int i = 0; i < 8; ++i) {
        int q = i * 256 + tid;          // chunk 0..2047
        int row = q >> 3, cst = q & 7;
        int cl = cst ^ (row & 7);
        gload_lds16((const char*)(gbase + (long)row * rstride + cl * 8), (char*)lds + q * 16);
    }
}
// Read staged V tile: row in [0,256) (d), k-slice = ks*32 + hi*8 (n within 64).
__device__ inline sh8 ldsV(const bf16* lds, int row, int ks, int hi) {
    return *(const sh8*)((const char*)lds + row * 128 + (((ks * 4 + hi) ^ (row & 7)) << 4));
}

// ---------------------------------------------------------------------------
// bf16 MFMA GEMM
// ---------------------------------------------------------------------------
template<int BN>
__global__ __launch_bounds__(256, 4)
void gemm_bf16(const bf16* __restrict__ A, int lda,
               const bf16* __restrict__ Bt, int ldb, long wstride,
               float* C, int ldc, bf16* Cbf,
               int M, int N, int K, int Kc,
               float alpha, const float* __restrict__ bias, long bstride,
               const float* res, int ldres, int flags,
               const bf16* __restrict__ zerobuf)
{
    constexpr int MI  = (BN == 128) ? 4 : 2;
    constexpr int BCH = BN * 8 / 256;
    __shared__ char smem[16384 + BN * 128];
    char* sA = smem;
    char* sB = smem + 16384;
    const int tid  = threadIdx.x;
    const int lane = tid & 63;
    const int lo   = lane & 15, hi = lane >> 4;
    const int wid  = tid >> 6;
    const int rowbase = (BN == 128) ? (wid >> 1) * 64 : wid * 32;
    const int colbase = (BN == 128) ? (wid & 1) * 64 : 0;
    const int bm = blockIdx.y * 128, bn = blockIdx.x * BN;

    const int eid = (blockIdx.y * 128) >> 11;
    const bf16* Bte = Bt + (long)eid * wstride;
    const float* biase = bias ? (bias + (long)eid * bstride) : nullptr;

    const int kbeg = blockIdx.z * Kc;
    const int kend = min(K, kbeg + Kc);

    fx4 acc[MI][4] = {};

    for (int k0 = kbeg; k0 < kend; k0 += 64) {
        #pragma unroll
        for (int i = 0; i < 4; ++i) {
            int id  = i * 256 + tid;
            int row = id >> 3;
            int c   = (id & 7) ^ (row & 7);
            int gk  = k0 + c * 8;
            const bf16* gp = (gk < kend) ? (A + (long)(bm + row) * lda + gk) : zerobuf;
            gload_lds16(gp, sA + id * 16);
        }
        #pragma unroll
        for (int i = 0; i < BCH; ++i) {
            int id  = i * 256 + tid;
            int row = id >> 3;
            int c   = (id & 7) ^ (row & 7);
            int gk  = k0 + c * 8;
            const bf16* gp = (gk < kend && bn + row < N) ? (Bte + (long)(bn + row) * ldb + gk)
                                                         : zerobuf;
            gload_lds16(gp, sB + id * 16);
        }
        asm volatile("s_waitcnt vmcnt(0)" ::: "memory");
        __syncthreads();

        #pragma unroll
        for (int kk = 0; kk < 2; ++kk) {
            const int ko = kk * 32 + hi * 8;
            sh8 af[MI], bfr[4];
            #pragma unroll
            for (int i = 0; i < MI; ++i) {
                int row = rowbase + i * 16 + lo;
                int off = (row * 128 + ko * 2) ^ ((row & 7) << 4);
                af[i] = *(const sh8*)(sA + off);
            }
            #pragma unroll
            for (int j = 0; j < 4; ++j) {
                int row = colbase + j * 16 + lo;
                int off = (row * 128 + ko * 2) ^ ((row & 7) << 4);
                bfr[j] = *(const sh8*)(sB + off);
            }
            #pragma unroll
            for (int i = 0; i < MI; ++i)
                #pragma unroll
                for (int j = 0; j < 4; ++j)
                    acc[i][j] = MFMA16(af[i], bfr[j], acc[i][j], 0, 0, 0);
        }
        __syncthreads();
    }

    const bool z0 = (blockIdx.z == 0);
    #pragma unroll
    for (int j = 0; j < 4; ++j) {
        int col = bn + colbase + j * 16 + lo;
        if (col >= N) continue;
        #pragma unroll
        for (int i = 0; i < MI; ++i) {
            #pragma unroll
            for (int r = 0; r < 4; ++r) {
                int row = bm + rowbase + i * 16 + hi * 4 + r;
                float v = alpha * acc[i][j][r];
                if (z0) {
                    if (biase) v += biase[col];
                    if (res)   v += res[(long)row * ldres + col];
                }
                if (flags & GF_RELU) v = fmaxf(v, 0.f);
                long idx = (long)row * ldc + col;
                if (flags & GF_ATOMIC) atomicAdd(&C[idx], v);
                else {
                    if (C)   C[idx] = v;
                    if (Cbf) Cbf[idx] = __float2bfloat16(v);
                }
            }
        }
    }
}

// ---------------------------------------------------------------------------
// Flash MHA (unstaged: K/V are L2-resident; padded Plds).
// ---------------------------------------------------------------------------
__global__ __launch_bounds__(256, 4)
void flash_mha(const bf16* __restrict__ qkv, const bf16* __restrict__ vT,
               bf16* __restrict__ obuf)
{
    const int e = blockIdx.z, h = blockIdx.y;
    const int n0 = blockIdx.x * 64;
    const int tid = threadIdx.x, lane = tid & 63, w = tid >> 6;
    const int lo = lane & 15, hi = lane >> 4;
    const float scaleH = 0.17677669529663687f;
    const bf16* qkv_e = qkv + (long)e * N_ * 768;
    const bf16* vT_eh = vT + ((long)e * D_ + h * 32) * N_;
    __shared__ bf16 Plds[4][16][72];

    sh8 qf = *(const sh8*)(qkv_e + (long)(n0 + w * 16 + lo) * 768 + h * 32 + hi * 8);

    float m[4], l[4];
    fx4 acc[2] = {};
    #pragma unroll
    for (int r = 0; r < 4; ++r) { m[r] = -INFINITY; l[r] = 0.f; }

    for (int kc = 0; kc < N_; kc += 64) {
        float sv[4][4], rmax[4], rsum[4];
        #pragma unroll
        for (int j = 0; j < 4; ++j) {
            sh8 kf = *(const sh8*)(qkv_e + (long)(kc + j * 16 + lo) * 768 + 256 + h * 32 + hi * 8);
            fx4 s = {};
            s = MFMA16(qf, kf, s, 0, 0, 0);
            #pragma unroll
            for (int r = 0; r < 4; ++r) sv[j][r] = s[r] * scaleH;
        }
        #pragma unroll
        for (int r = 0; r < 4; ++r)
            rmax[r] = fmaxf(fmaxf(sv[0][r], sv[1][r]), fmaxf(sv[2][r], sv[3][r]));
        #pragma unroll
        for (int d = 1; d < 16; d <<= 1)
            #pragma unroll
            for (int r = 0; r < 4; ++r) rmax[r] = fmaxf(rmax[r], __shfl_xor(rmax[r], d, 64));
        float sc[4];
        #pragma unroll
        for (int r = 0; r < 4; ++r) {
            float mn = fmaxf(m[r], rmax[r]);
            sc[r] = __expf(m[r] - mn);
            m[r] = mn; rsum[r] = 0.f;
        }
        #pragma unroll
        for (int j = 0; j < 4; ++j)
            #pragma unroll
            for (int r = 0; r < 4; ++r) {
                float p = __expf(sv[j][r] - m[r]);
                sv[j][r] = p; rsum[r] += p;
            }
        #pragma unroll
        for (int d = 1; d < 16; d <<= 1)
            #pragma unroll
            for (int r = 0; r < 4; ++r) rsum[r] += __shfl_xor(rsum[r], d, 64);
        #pragma unroll
        for (int r = 0; r < 4; ++r) l[r] = l[r] * sc[r] + rsum[r];
        #pragma unroll
        for (int j2 = 0; j2 < 2; ++j2)
            #pragma unroll
            for (int r = 0; r < 4; ++r) acc[j2][r] *= sc[r];
        #pragma unroll
        for (int j = 0; j < 4; ++j)
            #pragma unroll
            for (int r = 0; r < 4; ++r)
                Plds[w][hi * 4 + r][j * 16 + lo] = __float2bfloat16(sv[j][r]);
        asm volatile("s_waitcnt lgkmcnt(0)" ::: "memory");
        __builtin_amdgcn_sched_barrier(0);
        __builtin_amdgcn_s_setprio(1);
        #pragma unroll
        for (int ks = 0; ks < 2; ++ks) {
            sh8 pa = *(const sh8*)(&Plds[w][lo][ks * 32 + hi * 8]);
            #pragma unroll
            for (int j2 = 0; j2 < 2; ++j2) {
                sh8 vb = *(const sh8*)(vT_eh + (long)(j2 * 16 + lo) * N_ + kc + ks * 32 + hi * 8);
                acc[j2] = MFMA16(pa, vb, acc[j2], 0, 0, 0);
            }
        }
        __builtin_amdgcn_s_setprio(0);
    }
    #pragma unroll
    for (int j2 = 0; j2 < 2; ++j2)
        #pragma unroll
        for (int r = 0; r < 4; ++r) {
            long row = (long)e * N_ + n0 + w * 16 + hi * 4 + r;
            obuf[row * D_ + h * 32 + j2 * 16 + lo] = __float2bfloat16(acc[j2][r] / l[r]);
        }
}

// ---------------------------------------------------------------------------
// Flash cross-attention: grid (N/64, CCH, E). K + V tiles staged in LDS.
// ---------------------------------------------------------------------------
__global__ __launch_bounds__(256, 2)
void flash_cross(const bf16* __restrict__ tok, const bf16* __restrict__ tokT,
                 bf16* __restrict__ Opart, float2* __restrict__ ml)
{
    const int e = blockIdx.z, ch = blockIdx.y;
    const int n0 = blockIdx.x * 64;
    const int tid = threadIdx.x, lane = tid & 63, w = tid >> 6;
    const int lo = lane & 15, hi = lane >> 4;
    const float scaleD = 1.0f / 16.0f;
    __shared__ bf16 Kt[64 * 256];
    __shared__ bf16 Vt[256 * 64];
    __shared__ bf16 Plds[4][16][72];

    sh8 qf[8];
    {
        const bf16* qr = tok + ((long)e * N_ + n0 + w * 16 + lo) * D_;
        #pragma unroll
        for (int ks = 0; ks < 8; ++ks) qf[ks] = *(const sh8*)(qr + ks * 32 + hi * 8);
    }
    float m[4], l[4];
    fx4 acc[16] = {};
    #pragma unroll
    for (int r = 0; r < 4; ++r) { m[r] = -INFINITY; l[r] = 0.f; }

    for (int kc = ch * 768; kc < ch * 768 + 768; kc += 64) {
        const int seg = kc >> 11;
        const int src = (seg < e) ? seg : seg + 1;
        const int rowb = kc & 2047;
        stage_k64(tok + ((long)src * N_ + rowb) * D_, Kt, tid);
        stage_v64(tokT + (long)src * D_ * N_ + rowb, N_, Vt, tid);
        asm volatile("s_waitcnt vmcnt(0)" ::: "memory");
        __syncthreads();

        float sv[4][4], rmax[4], rsum[4];
        __builtin_amdgcn_s_setprio(1);
        #pragma unroll
        for (int j = 0; j < 4; ++j) {
            int krow = j * 16 + lo;
            fx4 s = {};
            #pragma unroll
            for (int ks = 0; ks < 8; ++ks) {
                sh8 kf = ldsK(Kt, krow, ks, hi);
                s = MFMA16(qf[ks], kf, s, 0, 0, 0);
            }
            #pragma unroll
            for (int r = 0; r < 4; ++r) sv[j][r] = s[r] * scaleD;
        }
        __builtin_amdgcn_s_setprio(0);
        #pragma unroll
        for (int r = 0; r < 4; ++r)
            rmax[r] = fmaxf(fmaxf(sv[0][r], sv[1][r]), fmaxf(sv[2][r], sv[3][r]));
        #pragma unroll
        for (int d = 1; d < 16; d <<= 1)
            #pragma unroll
            for (int r = 0; r < 4; ++r) rmax[r] = fmaxf(rmax[r], __shfl_xor(rmax[r], d, 64));
        float sc[4];
        #pragma unroll
        for (int r = 0; r < 4; ++r) {
            float mn = fmaxf(m[r], rmax[r]);
            sc[r] = __expf(m[r] - mn);
            m[r] = mn; rsum[r] = 0.f;
        }
        #pragma unroll
        for (int j = 0; j < 4; ++j)
            #pragma unroll
            for (int r = 0; r < 4; ++r) {
                float p = __expf(sv[j][r] - m[r]);
                sv[j][r] = p; rsum[r] += p;
            }
        #pragma unroll
        for (int d = 1; d < 16; d <<= 1)
            #pragma unroll
            for (int r = 0; r < 4; ++r) rsum[r] += __shfl_xor(rsum[r], d, 64);
        #pragma unroll
        for (int r = 0; r < 4; ++r) l[r] = l[r] * sc[r] + rsum[r];
        #pragma unroll
        for (int j2 = 0; j2 < 16; ++j2)
            #pragma unroll
            for (int r = 0; r < 4; ++r) acc[j2][r] *= sc[r];
        #pragma unroll
        for (int j = 0; j < 4; ++j)
            #pragma unroll
            for (int r = 0; r < 4; ++r)
                Plds[w][hi * 4 + r][j * 16 + lo] = __float2bfloat16(sv[j][r]);
        asm volatile("s_waitcnt lgkmcnt(0)" ::: "memory");
        __builtin_amdgcn_sched_barrier(0);
        __builtin_amdgcn_s_setprio(1);
        #pragma unroll
        for (int ks = 0; ks < 2; ++ks) {
            sh8 pa = *(const sh8*)(&Plds[w][lo][ks * 32 + hi * 8]);
            #pragma unroll
            for (int j2 = 0; j2 < 16; ++j2) {
                sh8 vb = ldsV(Vt, j2 * 16 + lo, ks, hi);
                acc[j2] = MFMA16(pa, vb, acc[j2], 0, 0, 0);
            }
        }
        __builtin_amdgcn_s_setprio(0);
        __syncthreads();
    }
    const long base = (long)ch * E_ * N_ + (long)e * N_ + n0 + w * 16;
    #pragma unroll
    for (int j2 = 0; j2 < 16; ++j2)
        #pragma unroll
        for (int r = 0; r < 4; ++r)
            Opart[(base + hi * 4 + r) * D_ + j2 * 16 + lo] = __float2bfloat16(acc[j2][r] / l[r]);
    if (lo == 0) {
        #pragma unroll
        for (int r = 0; r < 4; ++r) {
            float2 t; t.x = m[r]; t.y = l[r];
            ml[base + hi * 4 + r] = t;
        }
    }
}

// Merge chunk-partials + token residual.
__global__ void cross_merge(const bf16* __restrict__ Opart, const float2* __restrict__ ml,
                            const float* __restrict__ tokens,
                            float* __restrict__ x0f, bf16* __restrict__ x0bf)
{
    long row = blockIdx.x; int d = threadIdx.x;
    float2 v[CCH];
    float mx = -INFINITY;
    #pragma unroll
    for (int i = 0; i < CCH; ++i) { v[i] = ml[(long)i * E_ * N_ + row]; mx = fmaxf(mx, v[i].x); }
    float L = 0.f, o = 0.f;
    #pragma unroll
    for (int i = 0; i < CCH; ++i) {
        float wgt = v[i].y * __expf(v[i].x - mx);
        L += wgt;
        o += wgt * __bfloat162float(Opart[((long)i * E_ * N_ + row) * D_ + d]);
    }
    float val = tokens[row * D_ + d] + o / L;
    x0f[row * D_ + d] = val;
    x0bf[row * D_ + d] = __float2bfloat16(val);
}

// ---------------------------------------------------------------------------
// ret_flash: per (q-tile, layer, e*2+mhalf). K + V staged. Deferred l-reduce.
// ---------------------------------------------------------------------------
__global__ __launch_bounds__(256, 2)
void ret_flash(const bf16* __restrict__ x2b, const bf16* __restrict__ memb,
               const bf16* __restrict__ maggT, bf16* __restrict__ OmemH,
               float* __restrict__ rsH)
{
    const int li = blockIdx.y;
    const int e = blockIdx.z >> 1, mh = blockIdx.z & 1;
    const int n0 = blockIdx.x * 64;
    const int tid = threadIdx.x, lane = tid & 63, w = tid >> 6;
    const int lo = lane & 15, hi = lane >> 4;
    const float scaleD = 1.0f / 16.0f;
    __shared__ bf16 Kt[64 * 256];
    __shared__ bf16 Vt[256 * 64];
    __shared__ bf16 Plds[4][16][72];

    sh8 qf[8];
    {
        const bf16* qr = x2b + ((long)e * N_ + n0 + w * 16 + lo) * D_;
        #pragma unroll
        for (int ks = 0; ks < 8; ++ks) qf[ks] = *(const sh8*)(qr + ks * 32 + hi * 8);
    }
    float l[4] = {0.f, 0.f, 0.f, 0.f};
    fx4 acc[16] = {};
    const bf16* Kl = memb + (long)li * M_ * D_;
    const bf16* Vl = maggT + (long)li * D_ * M_;
    const int mbase = mh * 2048;

    for (int t = 0; t < 32; ++t) {
        const int m0 = mbase + t * 64;
        stage_k64(Kl + (long)m0 * D_, Kt, tid);
        stage_v64(Vl + m0, M_, Vt, tid);
        asm volatile("s_waitcnt vmcnt(0)" ::: "memory");
        __syncthreads();

        __builtin_amdgcn_s_setprio(1);
        #pragma unroll
        for (int j = 0; j < 4; ++j) {
            int krow = j * 16 + lo;
            fx4 s = {};
            #pragma unroll
            for (int ks = 0; ks < 8; ++ks) {
                sh8 kf = ldsK(Kt, krow, ks, hi);
                s = MFMA16(qf[ks], kf, s, 0, 0, 0);
            }
            #pragma unroll
            for (int r = 0; r < 4; ++r) {
                float p = __expf(s[r] * scaleD);
                l[r] += p;
                Plds[w][hi * 4 + r][j * 16 + lo] = __float2bfloat16(p);
            }
        }
        __builtin_amdgcn_s_setprio(0);
        asm volatile("s_waitcnt lgkmcnt(0)" ::: "memory");
        __builtin_amdgcn_sched_barrier(0);
        __builtin_amdgcn_s_setprio(1);
        #pragma unroll
        for (int ks = 0; ks < 2; ++ks) {
            sh8 pa = *(const sh8*)(&Plds[w][lo][ks * 32 + hi * 8]);
            #pragma unroll
            for (int j2 = 0; j2 < 16; ++j2) {
                sh8 vb = ldsV(Vt, j2 * 16 + lo, ks, hi);
                acc[j2] = MFMA16(pa, vb, acc[j2], 0, 0, 0);
            }
        }
        __builtin_amdgcn_s_setprio(0);
        __syncthreads();
    }
    #pragma unroll
    for (int d = 1; d < 16; d <<= 1)
        #pragma unroll
        for (int r = 0; r < 4; ++r) l[r] += __shfl_xor(l[r], d, 64);

    const long rowb = ((long)(mh * 12 + e * L_ + li)) * N_ + n0 + w * 16;
    #pragma unroll
    for (int j2 = 0; j2 < 16; ++j2)
        #pragma unroll
        for (int r = 0; r < 4; ++r)
            OmemH[(rowb + hi * 4 + r) * D_ + j2 * 16 + lo] = __float2bfloat16(acc[j2][r]);
    if (lo == 0) {
        #pragma unroll
        for (int r = 0; r < 4; ++r)
            rsH[rowb + hi * 4 + r] = l[r];
    }
}

// rsinv[i] = 1/(rsH[i] + rsH[12N + i])  for i in [0, 12N)
__global__ void rsinv_kernel(const float* __restrict__ rsH, float* __restrict__ rsinv) {
    long i = (long)blockIdx.x * 256 + threadIdx.x;
    if (i < (long)12 * N_)
        rsinv[i] = 1.0f / (rsH[i] + rsH[(long)12 * N_ + i]);
}

// ---------------------------------------------------------------------------
// upd_flash (R11): updpart[e][l][m][d] = (exp(mem@x2^T/16)*rsinv) @ x2. K + V staged.
// ---------------------------------------------------------------------------
__global__ __launch_bounds__(256, 2)
void upd_flash(const bf16* __restrict__ x2b, const bf16* __restrict__ memb,
               const bf16* __restrict__ x2T, const float* __restrict__ rsinv,
               bf16* __restrict__ updpart)
{
    const int li = blockIdx.y, e = blockIdx.z;
    const int m0 = blockIdx.x * 64;
    const int tid = threadIdx.x, lane = tid & 63, w = tid >> 6;
    const int lo = lane & 15, hi = lane >> 4;
    const float scaleD = 1.0f / 16.0f;
    __shared__ bf16 Kt[64 * 256];
    __shared__ bf16 Vt[256 * 64];
    __shared__ bf16 Plds[4][16][72];

    sh8 qf[8];
    {
        const bf16* qr = memb + (long)li * M_ * D_ + (long)(m0 + w * 16 + lo) * D_;
        #pragma unroll
        for (int ks = 0; ks < 8; ++ks) qf[ks] = *(const sh8*)(qr + ks * 32 + hi * 8);
    }
    fx4 acc[16] = {};
    const float* rse = rsinv + (long)(e * L_ + li) * N_;
    const bf16* x2Te = x2T + (long)e * D_ * N_;

    for (int t = 0; t < 32; ++t) {
        const int n0 = t * 64;
        stage_k64(x2b + ((long)e * N_ + n0) * D_, Kt, tid);
        stage_v64(x2Te + n0, N_, Vt, tid);
        float rinv[4];
        #pragma unroll
        for (int j = 0; j < 4; ++j) rinv[j] = rse[n0 + j * 16 + lo];
        asm volatile("s_waitcnt vmcnt(0)" ::: "memory");
        __syncthreads();

        __builtin_amdgcn_s_setprio(1);
        #pragma unroll
        for (int j = 0; j < 4; ++j) {
            int krow = j * 16 + lo;
            fx4 s = {};
            #pragma unroll
            for (int ks = 0; ks < 8; ++ks) {
                sh8 kf = ldsK(Kt, krow, ks, hi);
                s = MFMA16(qf[ks], kf, s, 0, 0, 0);
            }
            #pragma unroll
            for (int r = 0; r < 4; ++r) {
                float p = __expf(s[r] * scaleD) * rinv[j];
                Plds[w][hi * 4 + r][j * 16 + lo] = __float2bfloat16(p);
            }
        }
        __builtin_amdgcn_s_setprio(0);
        asm volatile("s_waitcnt lgkmcnt(0)" ::: "memory");
        __builtin_amdgcn_sched_barrier(0);
        __builtin_amdgcn_s_setprio(1);
        #pragma unroll
        for (int ks = 0; ks < 2; ++ks) {
            sh8 pa = *(const sh8*)(&Plds[w][lo][ks * 32 + hi * 8]);
            #pragma unroll
            for (int j2 = 0; j2 < 16; ++j2) {
                sh8 vb = ldsV(Vt, j2 * 16 + lo, ks, hi);
                acc[j2] = MFMA16(pa, vb, acc[j2], 0, 0, 0);
            }
        }
        __builtin_amdgcn_s_setprio(0);
        __syncthreads();
    }
    const long mrow = ((long)(e * L_ + li)) * M_ + m0 + w * 16;
    #pragma unroll
    for (int j2 = 0; j2 < 16; ++j2)
        #pragma unroll
        for (int r = 0; r < 4; ++r)
            updpart[(mrow + hi * 4 + r) * D_ + j2 * 16 + lo] = __float2bfloat16(acc[j2][r]);
}

// xfinal[e,n] += sum_l (O0+O1)*rsinv + agg_b
__global__ void retscale(const bf16* __restrict__ OmemH, const float* __restrict__ rsinv,
                         const float* __restrict__ aggb, float* __restrict__ xfinal)
{
    long row = blockIdx.x; int d = threadIdx.x;
    int e = (int)(row >> 11); long n = row & 2047;
    float s = aggb[d];
    #pragma unroll
    for (int li = 0; li < L_; ++li) {
        long r0 = ((long)(e * L_ + li)) * N_ + n;
        long r1 = ((long)(12 + e * L_ + li)) * N_ + n;
        float o = __bfloat162float(OmemH[r0 * D_ + d]) + __bfloat162float(OmemH[r1 * D_ + d]);
        s += o * rsinv[r0];
    }
    xfinal[row * D_ + d] += s;
}

// LayerNorm over D=256, per-expert weights (expert = row>>11). f32 + bf16 out.
__global__ void layernorm_rows(const float* __restrict__ X, const float* __restrict__ g,
                               const float* __restrict__ b, float* __restrict__ out,
                               bf16* __restrict__ outbf)
{
    __shared__ float red[256];
    int row = blockIdx.x, t = threadIdx.x;
    int e = row >> 11;
    float v = X[(long)row * 256 + t];
    red[t] = v; __syncthreads();
    for (int s = 128; s > 0; s >>= 1) { if (t < s) red[t] += red[t + s]; __syncthreads(); }
    float mu = red[0] * (1.0f / 256.0f); __syncthreads();
    float d = v - mu;
    red[t] = d * d; __syncthreads();
    for (int s = 128; s > 0; s >>= 1) { if (t < s) red[t] += red[t + s]; __syncthreads(); }
    float var = red[0] * (1.0f / 256.0f);
    float o = d * rsqrtf(var + EPS_) * g[e * 256 + t] + b[e * 256 + t];
    out[(long)row * 256 + t] = o;
    outbf[(long)row * 256 + t] = __float2bfloat16(o);
}

__global__ void cvt_bf16(const float* __restrict__ in, bf16* __restrict__ out, long n) {
    long i = ((long)blockIdx.x * 256 + threadIdx.x) * 4;
    if (i < n) {
        float4 v = *(const float4*)(in + i);
        out[i + 0] = __float2bfloat16(v.x);
        out[i + 1] = __float2bfloat16(v.y);
        out[i + 2] = __float2bfloat16(v.z);
        out[i + 3] = __float2bfloat16(v.w);
    }
}

__device__ inline float ldf(const float* p) { return *p; }
__device__ inline float ldf(const bf16* p)  { return __bfloat162float(*p); }

template<typename T>
__global__ void transpose_bf16(const T* __restrict__ in, bf16* __restrict__ out,
                               int R, int C, int ldin, int ldout) {
    __shared__ float t[64][65];
    int tx = threadIdx.x & 63, ty = threadIdx.x >> 6;
    int r0 = blockIdx.y * 64, c0 = blockIdx.x * 64;
    #pragma unroll
    for (int i = 0; i < 16; ++i) {
        int r = ty + i * 4;
        t[r][tx] = ldf(&in[(long)(r0 + r) * ldin + (c0 + tx)]);
    }
    __syncthreads();
    #pragma unroll
    for (int i = 0; i < 16; ++i) {
        int c = ty + i * 4;
        out[(long)(c0 + c) * ldout + (r0 + tx)] = __float2bfloat16(t[tx][c]);
    }
}

// out_mem = 0.9*mem + 0.1*sum_e updpart[e]
__global__ void mem_update(const float4* __restrict__ mem, const bf16* __restrict__ updpart,
                           float4* __restrict__ out) {
    long i = (long)blockIdx.x * 256 + threadIdx.x;
    const long LMD = (long)L_ * M_ * D_;
    if (i < LMD / 4) {
        float4 a = mem[i];
        float s0 = 0.f, s1 = 0.f, s2 = 0.f, s3 = 0.f;
        #pragma unroll
        for (int e = 0; e < E_; ++e) {
            const bf16* u = updpart + e * LMD + i * 4;
            s0 += __bfloat162float(u[0]);
            s1 += __bfloat162float(u[1]);
            s2 += __bfloat162float(u[2]);
            s3 += __bfloat162float(u[3]);
        }
        float4 r;
        r.x = (1.0f - GAMMA_) * a.x + GAMMA_ * s0;
        r.y = (1.0f - GAMMA_) * a.y + GAMMA_ * s1;
        r.z = (1.0f - GAMMA_) * a.z + GAMMA_ * s2;
        r.w = (1.0f - GAMMA_) * a.w + GAMMA_ * s3;
        out[i] = r;
    }
}

__global__ void pool_partial(const float* __restrict__ xf, float* __restrict__ pooled) {
    int e = blockIdx.x, chunk = blockIdx.y, t = threadIdx.x;
    float s = 0.f;
    int n0 = chunk * (N_ / 16);
    for (int n = n0; n < n0 + N_ / 16; ++n)
        s += xf[((long)e * N_ + n) * D_ + t];
    atomicAdd(&pooled[e * D_ + t], s * (1.0f / (float)N_));
}

__global__ void gate_kernel(const float* __restrict__ pooled, const float* __restrict__ gg,
                            float* __restrict__ out_gate, float* __restrict__ ws_gate) {
    __shared__ float red[256];
    __shared__ float logits[4];
    int t = threadIdx.x;
    for (int e = 0; e < 4; ++e) {
        red[t] = pooled[e * 256 + t] * gg[t];
        __syncthreads();
        for (int s = 128; s > 0; s >>= 1) { if (t < s) red[t] += red[t + s]; __syncthreads(); }
        if (t == 0) logits[e] = red[0];
        __syncthreads();
    }
    if (t == 0) {
        float mm = fmaxf(fmaxf(logits[0], logits[1]), fmaxf(logits[2], logits[3]));
        float g[4]; float s = 0.f;
        for (int e = 0; e < 4; ++e) { g[e] = __expf(logits[e] - mm); s += g[e]; }
        for (int e = 0; e < 4; ++e) {
            float w = g[e] / s;
            out_gate[e] = w;
            ws_gate[e] = w;
        }
    }
}

__global__ void fuse_kernel(const float* __restrict__ xf, const float* __restrict__ g4,
                            float* __restrict__ out) {
    long i = (long)blockIdx.x * 256 + threadIdx.x;
    const long ND = (long)N_ * D_;
    if (i < ND)
        out[i] = g4[0] * xf[i] + g4[1] * xf[ND + i] + g4[2] * xf[2 * ND + i] + g4[3] * xf[3 * ND + i];
}

// ---------------------------------------------------------------------------

static void gemm(hipStream_t s, int BN, const bf16* A, int lda, const bf16* Bt, int ldb,
                 long wstride, float* C, int ldc, bf16* Cbf, int M, int N, int K, int Kc,
                 float alpha, const float* bias, long bstride, const float* res, int ldres,
                 int flags, const bf16* zb) {
    dim3 g((N + BN - 1) / BN, (M + 127) / 128, (K + Kc - 1) / Kc);
    if (BN == 128)
        gemm_bf16<128><<<g, dim3(256), 0, s>>>(A, lda, Bt, ldb, wstride, C, ldc, Cbf, M, N, K, Kc,
                                               alpha, bias, bstride, res, ldres, flags, zb);
    else
        gemm_bf16<64><<<g, dim3(256), 0, s>>>(A, lda, Bt, ldb, wstride, C, ldc, Cbf, M, N, K, Kc,
                                              alpha, bias, bstride, res, ldres, flags, zb);
}

static void transposeF(hipStream_t s, const float* in, bf16* out, int R, int C, int ldin, int ldout) {
    transpose_bf16<float><<<dim3(C / 64, R / 64), dim3(256), 0, s>>>(in, out, R, C, ldin, ldout);
}
static void transposeB(hipStream_t s, const bf16* in, bf16* out, int R, int C, int ldin, int ldout) {
    transpose_bf16<bf16><<<dim3(C / 64, R / 64), dim3(256), 0, s>>>(in, out, R, C, ldin, ldout);
}
static void convert(hipStream_t s, const float* in, bf16* out, long n) {
    cvt_bf16<<<dim3((unsigned)((n / 4 + 255) / 256)), dim3(256), 0, s>>>(in, out, n);
}

extern "C" void kernel_launch(void* const* d_in, const int* in_sizes, int n_in,
                              void* d_out, int out_size, void* d_ws, size_t ws_size,
                              hipStream_t stream) {
    const float* tokens    = (const float*)d_in[0];
    const float* memories  = (const float*)d_in[1];
    const float* in_proj_w = (const float*)d_in[2];
    const float* in_proj_b = (const float*)d_in[3];
    const float* out_w     = (const float*)d_in[4];
    const float* out_b     = (const float*)d_in[5];
    const float* lin1_w    = (const float*)d_in[6];
    const float* lin1_b    = (const float*)d_in[7];
    const float* lin2_w    = (const float*)d_in[8];
    const float* lin2_b    = (const float*)d_in[9];
    const float* ln1_w     = (const float*)d_in[10];
    const float* ln1_b     = (const float*)d_in[11];
    const float* ln2_w     = (const float*)d_in[12];
    const float* ln2_b     = (const float*)d_in[13];
    const float* agg_w     = (const float*)d_in[14];
    const float* agg_b     = (const float*)d_in[15];
    const float* gg        = (const float*)d_in[16];

    char* p = (char*)d_ws;
    auto alloc = [&](size_t bytes) { char* r = p; p += (bytes + 255) & ~(size_t)255; return r; };

    // regionA (32MB), time-shared: Opart(cross) -> hid_all(FFN) -> OmemH(mem, bf16 halves)
    char*  regionA = alloc((size_t)32 * 1024 * 1024);
    bf16*  Opart   = (bf16*)regionA;                    // [8][E*N][256] bf16 = 32MB
    bf16*  hid_all = (bf16*)regionA;                    // [8192][2048] bf16 = 32MB
    bf16*  OmemH   = (bf16*)regionA;                    // [2][12][2048][256] bf16 = 25.2MB

    // regionB (32MB), time-shared: qkv|vT|obuf (MHA) -> updpart (mem)
    char*  regionB = alloc((size_t)32 * 1024 * 1024);
    bf16*  qkv_bf  = (bf16*)regionB;                              // 12.58MB
    bf16*  vT_bf   = (bf16*)(regionB + 12582912);                 // 4.19MB
    bf16*  obuf_bf = (bf16*)(regionB + 12582912 + 4194304);       // 4.19MB
    bf16*  updpart = (bf16*)regionB;                              // [4][3][4096][256] bf16 = 25.2MB

    float* xfinal  = (float*)alloc((size_t)E_ * N_ * D_ * 4);
    bf16*  x2_bf   = (bf16*)alloc((size_t)E_ * N_ * D_ * 2);
    bf16*  x2T_bf  = (bf16*)alloc((size_t)E_ * D_ * N_ * 2);
    float* x0f     = (float*)alloc((size_t)E_ * N_ * D_ * 4);
    bf16*  x0bf    = (bf16*)alloc((size_t)E_ * N_ * D_ * 2);
    float* ybuf    = (float*)alloc((size_t)E_ * N_ * D_ * 4);
    bf16*  tok_bf  = (bf16*)alloc((size_t)E_ * N_ * D_ * 2);
    bf16*  tokT_bf = (bf16*)alloc((size_t)E_ * D_ * N_ * 2);
    bf16*  mem_bf  = (bf16*)alloc((size_t)L_ * M_ * D_ * 2);
    bf16*  maggT   = (bf16*)alloc((size_t)L_ * D_ * M_ * 2);
    float2* mlbuf  = (float2*)alloc((size_t)CCH * E_ * N_ * sizeof(float2));
    float* rsH     = (float*)alloc((size_t)2 * 12 * N_ * 4);
    float* rsinv   = (float*)alloc((size_t)12 * N_ * 4);
    bf16*  ipw_bf  = (bf16*)alloc((size_t)E_ * 3 * D_ * D_ * 2);
    bf16*  outw_bf = (bf16*)alloc((size_t)E_ * D_ * D_ * 2);
    bf16*  l1w_bf  = (bf16*)alloc((size_t)E_ * F_ * D_ * 2);
    bf16*  l2w_bf  = (bf16*)alloc((size_t)E_ * D_ * F_ * 2);
    bf16*  aggw_bf = (bf16*)alloc((size_t)D_ * 3 * D_ * 2);
    float* pooled  = (float*)alloc(1024 * 4);
    float* gatebuf = (float*)alloc(64);
    bf16*  zerobuf = (bf16*)alloc(64);

    float* x1f  = x0f;
    bf16*  x1bf = x0bf;

    float* out_fused = (float*)d_out;
    float* out_gate  = out_fused + (long)N_ * D_;
    float* out_mem   = out_gate + E_;

    hipMemsetAsync(zerobuf, 0, 64, stream);
    hipMemsetAsync(pooled, 0, 1024 * 4, stream);

    // one-time conversions / transposes
    convert(stream, tokens, tok_bf, (long)E_ * N_ * D_);
    convert(stream, memories, mem_bf, (long)L_ * M_ * D_);
    convert(stream, in_proj_w, ipw_bf, (long)E_ * 3 * D_ * D_);
    convert(stream, out_w, outw_bf, (long)E_ * D_ * D_);
    convert(stream, lin1_w, l1w_bf, (long)E_ * F_ * D_);
    convert(stream, lin2_w, l2w_bf, (long)E_ * D_ * F_);
    convert(stream, agg_w, aggw_bf, (long)D_ * 3 * D_);
    for (int e = 0; e < E_; ++e)
        transposeF(stream, tokens + (long)e * N_ * D_, tokT_bf + (long)e * D_ * N_, N_, D_, D_, N_);
    // maggT_l = agg_w_l @ mem_l^T : [256, 4096]
    for (int l = 0; l < L_; ++l)
        gemm(stream, 128, aggw_bf + l * D_, 3 * D_, mem_bf + (long)l * M_ * D_, D_, 0,
             nullptr, M_, maggT + (long)l * D_ * M_, D_, M_, D_, D_,
             1.0f, nullptr, 0, nullptr, 0, 0, zerobuf);

    // ---- cross-expert attention ----
    flash_cross<<<dim3(N_ / 64, CCH, E_), dim3(256), 0, stream>>>(tok_bf, tokT_bf, Opart, mlbuf);
    cross_merge<<<dim3(E_ * N_), dim3(256), 0, stream>>>(Opart, mlbuf, tokens, x0f, x0bf);

    // ---- MHA (batched) ----
    gemm(stream, 128, x0bf, D_, ipw_bf, D_, (long)3 * D_ * D_,
         nullptr, 3 * D_, qkv_bf, E_ * N_, 3 * D_, D_, D_,
         1.0f, in_proj_b, 3 * D_, nullptr, 0, 0, zerobuf);
    for (int e = 0; e < E_; ++e)
        transposeB(stream, qkv_bf + (long)e * N_ * 3 * D_ + 2 * D_, vT_bf + (long)e * D_ * N_,
                   N_, D_, 3 * D_, N_);
    flash_mha<<<dim3(N_ / 64, H_, E_), dim3(256), 0, stream>>>(qkv_bf, vT_bf, obuf_bf);
    gemm(stream, 64, obuf_bf, D_, outw_bf, D_, (long)D_ * D_,
         ybuf, D_, nullptr, E_ * N_, D_, D_, D_,
         1.0f, out_b, D_, x0f, D_, 0, zerobuf);
    layernorm_rows<<<dim3(E_ * N_), dim3(256), 0, stream>>>(ybuf, ln1_w, ln1_b, x1f, x1bf);

    // ---- FFN (batched) ----
    gemm(stream, 128, x1bf, D_, l1w_bf, D_, (long)F_ * D_,
         nullptr, F_, hid_all, E_ * N_, F_, D_, D_,
         1.0f, lin1_b, F_, nullptr, 0, GF_RELU, zerobuf);
    hipMemsetAsync(ybuf, 0, (size_t)E_ * N_ * D_ * 4, stream);
    gemm(stream, 64, hid_all, F_, l2w_bf, F_, (long)D_ * F_,
         ybuf, D_, nullptr, E_ * N_, D_, F_, 512,
         1.0f, lin2_b, D_, x1f, D_, GF_ATOMIC, zerobuf);
    layernorm_rows<<<dim3(E_ * N_), dim3(256), 0, stream>>>(ybuf, ln2_w, ln2_b, xfinal, x2_bf);
    for (int e = 0; e < E_; ++e)
        transposeF(stream, xfinal + (long)e * N_ * D_, x2T_bf + (long)e * D_ * N_, N_, D_, D_, N_);

    // ---- memory read/write (flash, no-max softmax, store-only epilogues) ----
    ret_flash<<<dim3(N_ / 64, L_, E_ * 2), dim3(256), 0, stream>>>(x2_bf, mem_bf, maggT, OmemH, rsH);
    rsinv_kernel<<<dim3((12 * N_ + 255) / 256), dim3(256), 0, stream>>>(rsH, rsinv);
    upd_flash<<<dim3(M_ / 64, L_, E_), dim3(256), 0, stream>>>(x2_bf, mem_bf, x2T_bf, rsinv, updpart);
    retscale<<<dim3(E_ * N_), dim3(256), 0, stream>>>(OmemH, rsinv, agg_b, xfinal);

    mem_update<<<dim3(L_ * M_ * D_ / 4 / 256), dim3(256), 0, stream>>>(
        (const float4*)memories, updpart, (float4*)out_mem);
    pool_partial<<<dim3(E_, 16), dim3(256), 0, stream>>>(xfinal, pooled);
    gate_kernel<<<dim3(1), dim3(256), 0, stream>>>(pooled, gg, out_gate, gatebuf);
    fuse_kernel<<<dim3((N_ * D_ + 255) / 256), dim3(256), 0, stream>>>(xfinal, gatebuf, out_fused);
}